// Round 1
// baseline (3349.635 us; speedup 1.0000x reference)
//
#include <hip/hip_runtime.h>
#include <hip/hip_bf16.h>
#include <math.h>

#define VERY_NEG (-1e30f)

// Problem constants (from setup_inputs)
// B=128, S=256, H=256, C=20000, NODES=25000, A=8, NH=8, d=32, FF=1024
constexpr int Bc = 128, Sc = 256, Hc = 256, Cc = 20000, Ac = 8, NHc = 8, DHc = 32, FFc = 1024;
constexpr int Mc = Bc * Sc;  // 32768 rows

// ---------------------------------------------------------------------------
// Kernel 1: fused DAG attention embedding. One block (256 thr) per code c.
//   leaves/ancestors gather -> x=[8,512] in LDS -> h=relu(x@w1+b1) (each
//   thread owns output col j, accumulates 8 rows) -> s=h@w2+b2+mask ->
//   softmax over A=8 -> out[c] = sum_a alpha_a * (ancestors*m)[a,:]
//   Writes dict[(c+1)*256 + j]; block 0 also zeroes dict row 0.
// ---------------------------------------------------------------------------
__global__ __launch_bounds__(256) void dag_embed_kernel(
    const int* __restrict__ leaves, const int* __restrict__ ancestors,
    const float* __restrict__ masks, const float* __restrict__ emb,
    const float* __restrict__ w1, const float* __restrict__ b1,
    const float* __restrict__ w2, const float* __restrict__ b2,
    float* __restrict__ dict) {
  const int c = blockIdx.x;
  const int tid = threadIdx.x;
  __shared__ float xs[8][512];   // concat(leaves*m, ancestors*m) per a
  __shared__ int nl[8], na[8];
  __shared__ float ml[8];
  __shared__ float red[8][4];
  __shared__ float alpha[8];

  if (tid < 8) {
    nl[tid] = leaves[c * 8 + tid];
    na[tid] = ancestors[c * 8 + tid];
    ml[tid] = masks[c * 8 + tid];
  }
  __syncthreads();

  // Gather 16 embedding rows (8 leaves + 8 ancestors), scaled by mask.
  // 1024 float4 total, 4 per thread.
#pragma unroll
  for (int it = 0; it < 4; ++it) {
    int idx = tid + it * 256;      // 0..1023
    int a = idx >> 7;              // 128 float4 per a-row (512 floats)
    int j4 = idx & 127;
    int node = (j4 < 64) ? nl[a] : na[a];
    int col = (j4 & 63) * 4;
    float4 ev = *(const float4*)(emb + (size_t)node * 256 + col);
    float mm = ml[a];
    float4 r;
    r.x = ev.x * mm; r.y = ev.y * mm; r.z = ev.z * mm; r.w = ev.w * mm;
    *(float4*)&xs[a][j4 * 4] = r;
  }
  __syncthreads();

  // h[a][tid] = relu(b1[tid] + sum_i xs[a][i] * w1[i][tid])
  float acc[8];
  {
    float bb = b1[tid];
#pragma unroll
    for (int a = 0; a < 8; ++a) acc[a] = bb;
  }
  for (int i = 0; i < 512; i += 4) {
    float w0 = w1[(i + 0) * 256 + tid];
    float wA = w1[(i + 1) * 256 + tid];
    float wB = w1[(i + 2) * 256 + tid];
    float wC = w1[(i + 3) * 256 + tid];
#pragma unroll
    for (int a = 0; a < 8; ++a) {
      float4 xv = *(const float4*)&xs[a][i];  // broadcast across lanes
      acc[a] += xv.x * w0 + xv.y * wA + xv.z * wB + xv.w * wC;
    }
  }

  // s[a] = sum_j h[a][j]*w2[j]  (block reduction), + b2 + (1-m)*VERY_NEG
  float w2j = w2[tid];
#pragma unroll
  for (int a = 0; a < 8; ++a) {
    float p = fmaxf(acc[a], 0.f) * w2j;
#pragma unroll
    for (int off = 32; off > 0; off >>= 1) p += __shfl_down(p, off, 64);
    if ((tid & 63) == 0) red[a][tid >> 6] = p;
  }
  __syncthreads();
  if (tid == 0) {
    float b2v = b2[0];
    float s[8], mx = -INFINITY;
#pragma unroll
    for (int a = 0; a < 8; ++a) {
      s[a] = red[a][0] + red[a][1] + red[a][2] + red[a][3] + b2v +
             (1.f - ml[a]) * VERY_NEG;
      mx = fmaxf(mx, s[a]);
    }
    float e[8], sum = 0.f;
#pragma unroll
    for (int a = 0; a < 8; ++a) { e[a] = __expf(s[a] - mx); sum += e[a]; }
    float inv = 1.f / sum;
#pragma unroll
    for (int a = 0; a < 8; ++a) alpha[a] = e[a] * inv;
  }
  __syncthreads();

  // out[j] = sum_a alpha[a] * (ancestors*m)[a][j]  == xs[a][256+j]
  float o = 0.f;
#pragma unroll
  for (int a = 0; a < 8; ++a) o += alpha[a] * xs[a][256 + tid];
  dict[(size_t)(c + 1) * 256 + tid] = o;
  if (c == 0) dict[tid] = 0.f;  // dict row 0 = zeros
}

// ---------------------------------------------------------------------------
// Kernel 2: row gather (embedding lookup), float4-vectorized.
// out[row] = table[ids[row]] ; 32768 rows x 64 float4.
// ---------------------------------------------------------------------------
__global__ __launch_bounds__(256) void gather_rows_f4(
    const int* __restrict__ ids, const float4* __restrict__ table,
    float4* __restrict__ out) {
  int gid = blockIdx.x * 256 + threadIdx.x;  // 0 .. 2097151
  int row = gid >> 6;
  int c4 = gid & 63;
  out[gid] = table[(size_t)ids[row] * 64 + c4];
}

// ---------------------------------------------------------------------------
// Kernel 3: fp32 GEMM  C[M,N] = A[M,K] @ B[K,N] (+bias) (relu) (+resid)
// 64x64 tile per 256-thread block, 4x4 per thread, K-tile = 16.
// ---------------------------------------------------------------------------
__global__ __launch_bounds__(256) void gemm64(
    const float* __restrict__ A, const float* __restrict__ Bm,
    const float* __restrict__ bias, const float* __restrict__ resid,
    float* __restrict__ C, int M, int N, int K, int relu) {
  __shared__ float As[16][64];  // [k][m]
  __shared__ float Bs[16][64];  // [k][n]
  const int tid = threadIdx.x;
  const int tx = tid & 15, ty = tid >> 4;
  const int rowBase = blockIdx.y * 64;
  const int colBase = blockIdx.x * 64;
  const int am = tid >> 2;         // 0..63
  const int ak = (tid & 3) * 4;    // 0,4,8,12
  const int bk = tid >> 4;         // 0..15
  const int bn = (tid & 15) * 4;   // 0..60

  float acc[4][4] = {};
  for (int k0 = 0; k0 < K; k0 += 16) {
    float4 av = *(const float4*)(A + (size_t)(rowBase + am) * K + k0 + ak);
    float4 bv = *(const float4*)(Bm + (size_t)(k0 + bk) * N + colBase + bn);
    As[ak + 0][am] = av.x;
    As[ak + 1][am] = av.y;
    As[ak + 2][am] = av.z;
    As[ak + 3][am] = av.w;
    *(float4*)&Bs[bk][bn] = bv;
    __syncthreads();
#pragma unroll
    for (int kk = 0; kk < 16; ++kk) {
      float4 a4 = *(const float4*)&As[kk][ty * 4];
      float4 b4 = *(const float4*)&Bs[kk][tx * 4];
      float ar[4] = {a4.x, a4.y, a4.z, a4.w};
      float br[4] = {b4.x, b4.y, b4.z, b4.w};
#pragma unroll
      for (int ir = 0; ir < 4; ++ir)
#pragma unroll
        for (int ic = 0; ic < 4; ++ic) acc[ir][ic] += ar[ir] * br[ic];
    }
    __syncthreads();
  }

#pragma unroll
  for (int ir = 0; ir < 4; ++ir) {
    int row = rowBase + ty * 4 + ir;
    int col = colBase + tx * 4;
    float v[4] = {acc[ir][0], acc[ir][1], acc[ir][2], acc[ir][3]};
    if (bias) {
      float4 bz = *(const float4*)(bias + col);
      v[0] += bz.x; v[1] += bz.y; v[2] += bz.z; v[3] += bz.w;
    }
    if (relu) {
#pragma unroll
      for (int ic = 0; ic < 4; ++ic) v[ic] = fmaxf(v[ic], 0.f);
    }
    if (resid) {
      float4 rz = *(const float4*)(resid + (size_t)row * N + col);
      v[0] += rz.x; v[1] += rz.y; v[2] += rz.z; v[3] += rz.w;
    }
    float4 o; o.x = v[0]; o.y = v[1]; o.z = v[2]; o.w = v[3];
    *(float4*)(C + (size_t)row * N + col) = o;
  }
}

// ---------------------------------------------------------------------------
// Kernel 4: fused per-(b,h) attention. 1024 blocks, 256 thr.
// K,V tiles in LDS; each thread owns one q row; 2-pass (max, exp+accum).
// q/k/v/ctx layout: [B*S, H] row-major, head h occupies cols h*32..h*32+31.
// ---------------------------------------------------------------------------
__global__ __launch_bounds__(256) void attn_kernel(
    const float* __restrict__ q, const float* __restrict__ k,
    const float* __restrict__ v, const float* __restrict__ code_mask,
    float* __restrict__ ctx) {
  const int b = blockIdx.x >> 3;
  const int h = blockIdx.x & 7;
  const int tid = threadIdx.x;
  __shared__ float Ks[256][32];
  __shared__ float Vs[256][32];
  __shared__ float madd[256];
  const size_t base = ((size_t)b * 256) * 256 + h * 32;

#pragma unroll
  for (int it = 0; it < 8; ++it) {
    int idx = tid + it * 256;       // 0..2047
    int r = idx >> 3, d4 = (idx & 7) * 4;
    *(float4*)&Ks[r][d4] = *(const float4*)(k + base + (size_t)r * 256 + d4);
    *(float4*)&Vs[r][d4] = *(const float4*)(v + base + (size_t)r * 256 + d4);
  }
  madd[tid] = (1.f - code_mask[b * 256 + tid]) * VERY_NEG;
  __syncthreads();

  float4 qr[8];
#pragma unroll
  for (int d4 = 0; d4 < 8; ++d4)
    qr[d4] = *(const float4*)(q + base + (size_t)tid * 256 + d4 * 4);

  const float scale = 0.17677669529663687f;  // 1/sqrt(32)

  float mx = -INFINITY;
  for (int kk = 0; kk < 256; ++kk) {
    float s = 0.f;
#pragma unroll
    for (int d4 = 0; d4 < 8; ++d4) {
      float4 kv = *(const float4*)&Ks[kk][d4 * 4];
      s += qr[d4].x * kv.x + qr[d4].y * kv.y + qr[d4].z * kv.z + qr[d4].w * kv.w;
    }
    s = s * scale + madd[kk];
    mx = fmaxf(mx, s);
  }

  float4 acc[8];
#pragma unroll
  for (int d4 = 0; d4 < 8; ++d4) { acc[d4].x = 0; acc[d4].y = 0; acc[d4].z = 0; acc[d4].w = 0; }
  float l = 0.f;
  for (int kk = 0; kk < 256; ++kk) {
    float s = 0.f;
#pragma unroll
    for (int d4 = 0; d4 < 8; ++d4) {
      float4 kv = *(const float4*)&Ks[kk][d4 * 4];
      s += qr[d4].x * kv.x + qr[d4].y * kv.y + qr[d4].z * kv.z + qr[d4].w * kv.w;
    }
    s = s * scale + madd[kk];
    float w = __expf(s - mx);
    l += w;
#pragma unroll
    for (int d4 = 0; d4 < 8; ++d4) {
      float4 vv = *(const float4*)&Vs[kk][d4 * 4];
      acc[d4].x += w * vv.x; acc[d4].y += w * vv.y;
      acc[d4].z += w * vv.z; acc[d4].w += w * vv.w;
    }
  }
  float inv = 1.f / l;
#pragma unroll
  for (int d4 = 0; d4 < 8; ++d4) {
    float4 o;
    o.x = acc[d4].x * inv; o.y = acc[d4].y * inv;
    o.z = acc[d4].z * inv; o.w = acc[d4].w * inv;
    *(float4*)(ctx + base + (size_t)tid * 256 + d4 * 4) = o;
  }
}

// ---------------------------------------------------------------------------
// Kernel 5: attention pooling. 128 blocks (one per batch), 256 thr.
// ---------------------------------------------------------------------------
__global__ __launch_bounds__(256) void pool_kernel(
    const float* __restrict__ x, const float* __restrict__ code_mask,
    const float* __restrict__ pw, const float* __restrict__ pb,
    float* __restrict__ out) {
  const int b = blockIdx.x;
  const int t = threadIdx.x;
  __shared__ float ss[256];
  __shared__ float red[256];
  __shared__ float als[256];
  const float* xb = x + (size_t)b * 256 * 256;

  float s = pb[0];
  for (int j = 0; j < 256; j += 4) {
    float4 xv = *(const float4*)(xb + (size_t)t * 256 + j);
    float4 wv = *(const float4*)(pw + j);
    s += xv.x * wv.x + xv.y * wv.y + xv.z * wv.z + xv.w * wv.w;
  }
  s += (1.f - code_mask[b * 256 + t]) * VERY_NEG;
  ss[t] = s; red[t] = s;
  __syncthreads();
  for (int off = 128; off > 0; off >>= 1) {
    if (t < off) red[t] = fmaxf(red[t], red[t + off]);
    __syncthreads();
  }
  float m = red[0];
  __syncthreads();
  float e = __expf(ss[t] - m);
  als[t] = e; red[t] = e;
  __syncthreads();
  for (int off = 128; off > 0; off >>= 1) {
    if (t < off) red[t] += red[t + off];
    __syncthreads();
  }
  float inv = 1.f / red[0];
  float o = 0.f;
  for (int si = 0; si < 256; ++si) o += als[si] * xb[(size_t)si * 256 + t];
  out[b * 256 + t] = o * inv;
}

// ---------------------------------------------------------------------------
extern "C" void kernel_launch(void* const* d_in, const int* in_sizes, int n_in,
                              void* d_out, int out_size, void* d_ws,
                              size_t ws_size, hipStream_t stream) {
  const int* input_ids = (const int*)d_in[0];
  const float* code_mask = (const float*)d_in[1];
  const int* dx_leaves = (const int*)d_in[2];
  const int* dx_anc = (const int*)d_in[3];
  const float* dx_masks = (const float*)d_in[4];
  const float* embed_init_w = (const float*)d_in[5];
  const float* embed_inputs_w = (const float*)d_in[6];
  const float* attn_w1 = (const float*)d_in[7];
  const float* attn_b1 = (const float*)d_in[8];
  const float* attn_w2 = (const float*)d_in[9];
  const float* attn_b2 = (const float*)d_in[10];
  const float* pool_w = (const float*)d_in[11];
  const float* pool_b = (const float*)d_in[12];

  float* out = (float*)d_out;
  float* ws = (float*)d_ws;

  // workspace layout (floats)
  float* dict = ws;                      // (C+1)*H = 5,120,256
  float* xbuf = dict + 5120256;          // 8,388,608
  float* qb   = xbuf + 8388608;          // 8,388,608
  float* kb   = qb + 8388608;            // 8,388,608
  float* vb   = kb + 8388608;            // 8,388,608
  float* ctxb = vb + 8388608;            // 8,388,608
  float* hid  = qb;                      // FFN hidden chunk aliases dead q

  // 1) DAG embedding -> dict_matrix
  dag_embed_kernel<<<Cc, 256, 0, stream>>>(dx_leaves, dx_anc, dx_masks,
                                           embed_init_w, attn_w1, attn_b1,
                                           attn_w2, attn_b2, dict);

  auto run_encoder = [&](const float* wq, const float* wk, const float* wv,
                         const float* wo, const float* fw1, const float* fb1,
                         const float* fw2, const float* fb2, float* final_out) {
    // QKV
    gemm64<<<dim3(4, 512), 256, 0, stream>>>(xbuf, wq, nullptr, nullptr, qb,
                                             Mc, Hc, Hc, 0);
    gemm64<<<dim3(4, 512), 256, 0, stream>>>(xbuf, wk, nullptr, nullptr, kb,
                                             Mc, Hc, Hc, 0);
    gemm64<<<dim3(4, 512), 256, 0, stream>>>(xbuf, wv, nullptr, nullptr, vb,
                                             Mc, Hc, Hc, 0);
    // attention -> ctx
    attn_kernel<<<Bc * NHc, 256, 0, stream>>>(qb, kb, vb, code_mask, ctxb);
    // x = x + ctx @ wo   (in-place residual)
    gemm64<<<dim3(4, 512), 256, 0, stream>>>(ctxb, wo, nullptr, xbuf, xbuf,
                                             Mc, Hc, Hc, 0);
    // FFN in 4 row-chunks of 8192 (hidden buffer = 8192x1024)
    for (int c4 = 0; c4 < 4; ++c4) {
      float* xc = xbuf + (size_t)c4 * 8192 * 256;
      float* oc = final_out + (size_t)c4 * 8192 * 256;
      gemm64<<<dim3(16, 128), 256, 0, stream>>>(xc, fw1, fb1, nullptr, hid,
                                                8192, FFc, Hc, 1);
      gemm64<<<dim3(4, 128), 256, 0, stream>>>(hid, fw2, fb2, xc, oc,
                                               8192, Hc, FFc, 0);
    }
  };

  // 2) visit stream: x = embed_inputs_w[ids]; encoder -> d_out[0:8388608]
  gather_rows_f4<<<8192, 256, 0, stream>>>(input_ids,
                                           (const float4*)embed_inputs_w,
                                           (float4*)xbuf);
  run_encoder((const float*)d_in[13], (const float*)d_in[14],
              (const float*)d_in[15], (const float*)d_in[16],
              (const float*)d_in[17], (const float*)d_in[18],
              (const float*)d_in[19], (const float*)d_in[20], out);

  // 3) dag stream: x = dict[ids]; encoder (in-place into xbuf); pooling
  gather_rows_f4<<<8192, 256, 0, stream>>>(input_ids, (const float4*)dict,
                                           (float4*)xbuf);
  run_encoder((const float*)d_in[21], (const float*)d_in[22],
              (const float*)d_in[23], (const float*)d_in[24],
              (const float*)d_in[25], (const float*)d_in[26],
              (const float*)d_in[27], (const float*)d_in[28], xbuf);

  pool_kernel<<<Bc, 256, 0, stream>>>(xbuf, code_mask, pool_w, pool_b,
                                      out + 8388608);
}

// Round 2
// 2562.868 us; speedup vs baseline: 1.3070x; 1.3070x over previous
//
#include <hip/hip_runtime.h>
#include <hip/hip_bf16.h>
#include <math.h>

#define VERY_NEG (-1e30f)

// Problem constants (from setup_inputs)
// B=128, S=256, H=256, C=20000, NODES=25000, A=8, NH=8, d=32, FF=1024
constexpr int Bc = 128, Sc = 256, Hc = 256, Cc = 20000, Ac = 8, NHc = 8, DHc = 32, FFc = 1024;
constexpr int Mc = Bc * Sc;  // 32768 rows
constexpr int Rc = Cc * Ac;  // 160000 dag rows

typedef __attribute__((ext_vector_type(8))) short short8;
typedef __attribute__((ext_vector_type(4))) float floatx4;

static __device__ __forceinline__ unsigned short f2bf(float f) {
  union { float f; unsigned u; } v; v.f = f;
  unsigned r = v.u + 0x7FFF + ((v.u >> 16) & 1);   // RNE
  return (unsigned short)(r >> 16);
}
static __device__ __forceinline__ unsigned pack2(float lo, float hi) {
  return (unsigned)f2bf(lo) | ((unsigned)f2bf(hi) << 16);
}

// ---------------------------------------------------------------------------
// DAG stage 0: w1 [512,256] fp32 -> w1T [256,512] bf16 (transposed+converted)
// ---------------------------------------------------------------------------
__global__ __launch_bounds__(256) void prep_w1T(const float* __restrict__ w1,
                                                unsigned short* __restrict__ w1T) {
  int gid = blockIdx.x * 256 + threadIdx.x;  // 0..131071
  int n = gid >> 9, k = gid & 511;
  w1T[(size_t)n * 512 + k] = f2bf(w1[(size_t)k * 256 + n]);
}

// ---------------------------------------------------------------------------
// DAG stage 1: build A [160000, 512] bf16 = concat(leaves_emb*m, anc_emb*m)
// row = c*8+a (same flat index as leaves/anc/masks). 4 rows per block.
// ---------------------------------------------------------------------------
__global__ __launch_bounds__(256) void build_A(
    const int* __restrict__ leaves, const int* __restrict__ anc,
    const float* __restrict__ masks, const float* __restrict__ emb,
    unsigned short* __restrict__ A) {
  int t = threadIdx.x;
  int row = blockIdx.x * 4 + (t >> 6);
  int lane = t & 63;
  int node = (lane < 32) ? leaves[row] : anc[row];
  float m = masks[row];
  int col = (lane & 31) * 8;  // 0..248 within the emb row
  const float* src = emb + (size_t)node * 256 + col;
  float4 a = ((const float4*)src)[0];
  float4 b = ((const float4*)src)[1];
  uint4 o;
  o.x = pack2(a.x * m, a.y * m);
  o.y = pack2(a.z * m, a.w * m);
  o.z = pack2(b.x * m, b.y * m);
  o.w = pack2(b.z * m, b.w * m);
  *(uint4*)(A + (size_t)row * 512 + lane * 8) = o;
}

// ---------------------------------------------------------------------------
// DAG stage 2: bf16 MFMA GEMM [160000,512]@[512,256] with fused epilogue
//   s[row] += sum_col relu(acc+b1[col]) * w2[col]
// 128x128 tile, 4 waves (2x2 of 64x64), 16x16x32 MFMA, BK=32, LDS pad +8.
// Grid: (N/128=2, M/128=1250). s must be pre-zeroed.
// ---------------------------------------------------------------------------
__global__ __launch_bounds__(256) void mlp_gemm(
    const unsigned short* __restrict__ A, const unsigned short* __restrict__ Bt,
    const float* __restrict__ b1, const float* __restrict__ w2,
    float* __restrict__ s) {
  __shared__ unsigned short As[128][40];  // +8 pad: row stride 80B breaks b128 conflicts
  __shared__ unsigned short Bs[128][40];
  const int tid = threadIdx.x;
  const int rowBase = blockIdx.y * 128;
  const int colBase = blockIdx.x * 128;
  const int wave = tid >> 6, lane = tid & 63;
  const int wm = wave >> 1, wn = wave & 1;
  const int quad = lane >> 4, l15 = lane & 15;
  const int r0 = tid >> 2, seg = tid & 3;

  floatx4 acc[4][4];
#pragma unroll
  for (int mt = 0; mt < 4; ++mt)
#pragma unroll
    for (int nt = 0; nt < 4; ++nt) acc[mt][nt] = (floatx4){0.f, 0.f, 0.f, 0.f};

  for (int k0 = 0; k0 < 512; k0 += 32) {
#pragma unroll
    for (int it = 0; it < 2; ++it) {
      int r = r0 + it * 64;
      *(uint4*)&As[r][seg * 8] =
          *(const uint4*)(A + (size_t)(rowBase + r) * 512 + k0 + seg * 8);
      *(uint4*)&Bs[r][seg * 8] =
          *(const uint4*)(Bt + (size_t)(colBase + r) * 512 + k0 + seg * 8);
    }
    __syncthreads();
    short8 af[4], bfr[4];
#pragma unroll
    for (int mt = 0; mt < 4; ++mt)
      af[mt] = *(const short8*)&As[wm * 64 + mt * 16 + l15][quad * 8];
#pragma unroll
    for (int nt = 0; nt < 4; ++nt)
      bfr[nt] = *(const short8*)&Bs[wn * 64 + nt * 16 + l15][quad * 8];
#pragma unroll
    for (int mt = 0; mt < 4; ++mt)
#pragma unroll
      for (int nt = 0; nt < 4; ++nt)
        acc[mt][nt] = __builtin_amdgcn_mfma_f32_16x16x32_bf16(
            af[mt], bfr[nt], acc[mt][nt], 0, 0, 0);
    __syncthreads();
  }

  // Fused epilogue: relu(h + b1) . w2 -> per-row partial, atomicAdd.
  float b1c[4], w2c[4];
#pragma unroll
  for (int nt = 0; nt < 4; ++nt) {
    int col = colBase + wn * 64 + nt * 16 + l15;
    b1c[nt] = b1[col];
    w2c[nt] = w2[col];
  }
#pragma unroll
  for (int mt = 0; mt < 4; ++mt) {
#pragma unroll
    for (int i = 0; i < 4; ++i) {
      float p = 0.f;
#pragma unroll
      for (int nt = 0; nt < 4; ++nt) {
        float v = acc[mt][nt][i] + b1c[nt];
        p += fmaxf(v, 0.f) * w2c[nt];
      }
      p += __shfl_xor(p, 1, 64);
      p += __shfl_xor(p, 2, 64);
      p += __shfl_xor(p, 4, 64);
      p += __shfl_xor(p, 8, 64);
      if (l15 == 0)
        atomicAdd(s + rowBase + wm * 64 + mt * 16 + quad * 4 + i, p);
    }
  }
}

// ---------------------------------------------------------------------------
// DAG stage 3: softmax over A=8 + masked ancestor weighted sum -> dict.
// One block per code.
// ---------------------------------------------------------------------------
__global__ __launch_bounds__(256) void dag_finalize(
    const float* __restrict__ s, const float* __restrict__ masks,
    const int* __restrict__ anc, const float* __restrict__ b2,
    const float* __restrict__ emb, float* __restrict__ dict) {
  const int c = blockIdx.x;
  const int t = threadIdx.x;
  __shared__ float sv[8], mv[8];
  __shared__ int nv[8];
  if (t < 8) {
    float m = masks[c * 8 + t];
    sv[t] = s[c * 8 + t] + b2[0] + (1.f - m) * VERY_NEG;
    mv[t] = m;
    nv[t] = anc[c * 8 + t];
  }
  __syncthreads();
  float mx = -INFINITY;
#pragma unroll
  for (int a = 0; a < 8; ++a) mx = fmaxf(mx, sv[a]);
  float e[8], sum = 0.f;
#pragma unroll
  for (int a = 0; a < 8; ++a) { e[a] = __expf(sv[a] - mx); sum += e[a]; }
  float inv = 1.f / sum;
  float o = 0.f;
#pragma unroll
  for (int a = 0; a < 8; ++a)
    o += e[a] * inv * mv[a] * emb[(size_t)nv[a] * 256 + t];
  dict[(size_t)(c + 1) * 256 + t] = o;
  if (c == 0) dict[t] = 0.f;  // dict row 0 = zeros
}

// ---------------------------------------------------------------------------
// Row gather (embedding lookup), float4-vectorized.
// ---------------------------------------------------------------------------
__global__ __launch_bounds__(256) void gather_rows_f4(
    const int* __restrict__ ids, const float4* __restrict__ table,
    float4* __restrict__ out) {
  int gid = blockIdx.x * 256 + threadIdx.x;
  int row = gid >> 6;
  int c4 = gid & 63;
  out[gid] = table[(size_t)ids[row] * 64 + c4];
}

// ---------------------------------------------------------------------------
// fp32 GEMM  C[M,N] = A[M,K] @ B[K,N] (+bias) (relu) (+resid)
// 64x64 tile per 256-thread block, 4x4 per thread, K-tile = 16.
// ---------------------------------------------------------------------------
__global__ __launch_bounds__(256) void gemm64(
    const float* __restrict__ A, const float* __restrict__ Bm,
    const float* __restrict__ bias, const float* __restrict__ resid,
    float* __restrict__ C, int M, int N, int K, int relu) {
  __shared__ float As[16][64];  // [k][m]
  __shared__ float Bs[16][64];  // [k][n]
  const int tid = threadIdx.x;
  const int tx = tid & 15, ty = tid >> 4;
  const int rowBase = blockIdx.y * 64;
  const int colBase = blockIdx.x * 64;
  const int am = tid >> 2;
  const int ak = (tid & 3) * 4;
  const int bk = tid >> 4;
  const int bn = (tid & 15) * 4;

  float acc[4][4] = {};
  for (int k0 = 0; k0 < K; k0 += 16) {
    float4 av = *(const float4*)(A + (size_t)(rowBase + am) * K + k0 + ak);
    float4 bv = *(const float4*)(Bm + (size_t)(k0 + bk) * N + colBase + bn);
    As[ak + 0][am] = av.x;
    As[ak + 1][am] = av.y;
    As[ak + 2][am] = av.z;
    As[ak + 3][am] = av.w;
    *(float4*)&Bs[bk][bn] = bv;
    __syncthreads();
#pragma unroll
    for (int kk = 0; kk < 16; ++kk) {
      float4 a4 = *(const float4*)&As[kk][ty * 4];
      float4 b4 = *(const float4*)&Bs[kk][tx * 4];
      float ar[4] = {a4.x, a4.y, a4.z, a4.w};
      float br[4] = {b4.x, b4.y, b4.z, b4.w};
#pragma unroll
      for (int ir = 0; ir < 4; ++ir)
#pragma unroll
        for (int ic = 0; ic < 4; ++ic) acc[ir][ic] += ar[ir] * br[ic];
    }
    __syncthreads();
  }

#pragma unroll
  for (int ir = 0; ir < 4; ++ir) {
    int row = rowBase + ty * 4 + ir;
    int col = colBase + tx * 4;
    float v[4] = {acc[ir][0], acc[ir][1], acc[ir][2], acc[ir][3]};
    if (bias) {
      float4 bz = *(const float4*)(bias + col);
      v[0] += bz.x; v[1] += bz.y; v[2] += bz.z; v[3] += bz.w;
    }
    if (relu) {
#pragma unroll
      for (int ic = 0; ic < 4; ++ic) v[ic] = fmaxf(v[ic], 0.f);
    }
    if (resid) {
      float4 rz = *(const float4*)(resid + (size_t)row * N + col);
      v[0] += rz.x; v[1] += rz.y; v[2] += rz.z; v[3] += rz.w;
    }
    float4 o; o.x = v[0]; o.y = v[1]; o.z = v[2]; o.w = v[3];
    *(float4*)(C + (size_t)row * N + col) = o;
  }
}

// ---------------------------------------------------------------------------
// Fused per-(b,h) attention. 1024 blocks, 256 thr.
// ---------------------------------------------------------------------------
__global__ __launch_bounds__(256) void attn_kernel(
    const float* __restrict__ q, const float* __restrict__ k,
    const float* __restrict__ v, const float* __restrict__ code_mask,
    float* __restrict__ ctx) {
  const int b = blockIdx.x >> 3;
  const int h = blockIdx.x & 7;
  const int tid = threadIdx.x;
  __shared__ float Ks[256][32];
  __shared__ float Vs[256][32];
  __shared__ float madd[256];
  const size_t base = ((size_t)b * 256) * 256 + h * 32;

#pragma unroll
  for (int it = 0; it < 8; ++it) {
    int idx = tid + it * 256;
    int r = idx >> 3, d4 = (idx & 7) * 4;
    *(float4*)&Ks[r][d4] = *(const float4*)(k + base + (size_t)r * 256 + d4);
    *(float4*)&Vs[r][d4] = *(const float4*)(v + base + (size_t)r * 256 + d4);
  }
  madd[tid] = (1.f - code_mask[b * 256 + tid]) * VERY_NEG;
  __syncthreads();

  float4 qr[8];
#pragma unroll
  for (int d4 = 0; d4 < 8; ++d4)
    qr[d4] = *(const float4*)(q + base + (size_t)tid * 256 + d4 * 4);

  const float scale = 0.17677669529663687f;  // 1/sqrt(32)

  float mx = -INFINITY;
  for (int kk = 0; kk < 256; ++kk) {
    float s = 0.f;
#pragma unroll
    for (int d4 = 0; d4 < 8; ++d4) {
      float4 kv = *(const float4*)&Ks[kk][d4 * 4];
      s += qr[d4].x * kv.x + qr[d4].y * kv.y + qr[d4].z * kv.z + qr[d4].w * kv.w;
    }
    s = s * scale + madd[kk];
    mx = fmaxf(mx, s);
  }

  float4 acc[8];
#pragma unroll
  for (int d4 = 0; d4 < 8; ++d4) { acc[d4].x = 0; acc[d4].y = 0; acc[d4].z = 0; acc[d4].w = 0; }
  float l = 0.f;
  for (int kk = 0; kk < 256; ++kk) {
    float s = 0.f;
#pragma unroll
    for (int d4 = 0; d4 < 8; ++d4) {
      float4 kv = *(const float4*)&Ks[kk][d4 * 4];
      s += qr[d4].x * kv.x + qr[d4].y * kv.y + qr[d4].z * kv.z + qr[d4].w * kv.w;
    }
    s = s * scale + madd[kk];
    float w = __expf(s - mx);
    l += w;
#pragma unroll
    for (int d4 = 0; d4 < 8; ++d4) {
      float4 vv = *(const float4*)&Vs[kk][d4 * 4];
      acc[d4].x += w * vv.x; acc[d4].y += w * vv.y;
      acc[d4].z += w * vv.z; acc[d4].w += w * vv.w;
    }
  }
  float inv = 1.f / l;
#pragma unroll
  for (int d4 = 0; d4 < 8; ++d4) {
    float4 o;
    o.x = acc[d4].x * inv; o.y = acc[d4].y * inv;
    o.z = acc[d4].z * inv; o.w = acc[d4].w * inv;
    *(float4*)(ctx + base + (size_t)tid * 256 + d4 * 4) = o;
  }
}

// ---------------------------------------------------------------------------
// Attention pooling. 128 blocks (one per batch), 256 thr.
// ---------------------------------------------------------------------------
__global__ __launch_bounds__(256) void pool_kernel(
    const float* __restrict__ x, const float* __restrict__ code_mask,
    const float* __restrict__ pw, const float* __restrict__ pb,
    float* __restrict__ out) {
  const int b = blockIdx.x;
  const int t = threadIdx.x;
  __shared__ float ss[256];
  __shared__ float red[256];
  __shared__ float als[256];
  const float* xb = x + (size_t)b * 256 * 256;

  float s = pb[0];
  for (int j = 0; j < 256; j += 4) {
    float4 xv = *(const float4*)(xb + (size_t)t * 256 + j);
    float4 wv = *(const float4*)(pw + j);
    s += xv.x * wv.x + xv.y * wv.y + xv.z * wv.z + xv.w * wv.w;
  }
  s += (1.f - code_mask[b * 256 + t]) * VERY_NEG;
  ss[t] = s; red[t] = s;
  __syncthreads();
  for (int off = 128; off > 0; off >>= 1) {
    if (t < off) red[t] = fmaxf(red[t], red[t + off]);
    __syncthreads();
  }
  float m = red[0];
  __syncthreads();
  float e = __expf(ss[t] - m);
  als[t] = e; red[t] = e;
  __syncthreads();
  for (int off = 128; off > 0; off >>= 1) {
    if (t < off) red[t] += red[t + off];
    __syncthreads();
  }
  float inv = 1.f / red[0];
  float o = 0.f;
  for (int si = 0; si < 256; ++si) o += als[si] * xb[(size_t)si * 256 + t];
  out[b * 256 + t] = o * inv;
}

// ---------------------------------------------------------------------------
extern "C" void kernel_launch(void* const* d_in, const int* in_sizes, int n_in,
                              void* d_out, int out_size, void* d_ws,
                              size_t ws_size, hipStream_t stream) {
  const int* input_ids = (const int*)d_in[0];
  const float* code_mask = (const float*)d_in[1];
  const int* dx_leaves = (const int*)d_in[2];
  const int* dx_anc = (const int*)d_in[3];
  const float* dx_masks = (const float*)d_in[4];
  const float* embed_init_w = (const float*)d_in[5];
  const float* embed_inputs_w = (const float*)d_in[6];
  const float* attn_w1 = (const float*)d_in[7];
  const float* attn_b1 = (const float*)d_in[8];
  const float* attn_w2 = (const float*)d_in[9];
  const float* attn_b2 = (const float*)d_in[10];
  const float* pool_w = (const float*)d_in[11];
  const float* pool_b = (const float*)d_in[12];

  float* out = (float*)d_out;
  float* ws = (float*)d_ws;

  // workspace layout (floats)
  float* dict = ws;                      // (C+1)*H = 5,120,256
  float* xbuf = dict + 5120256;          // 8,388,608
  float* qb   = xbuf + 8388608;          // 8,388,608
  float* kb   = qb + 8388608;            // 8,388,608
  float* vb   = kb + 8388608;            // 8,388,608
  float* ctxb = vb + 8388608;            // 8,388,608
  float* hid  = qb;                      // FFN hidden chunk aliases dead q

  // DAG-phase aliases over the (currently dead) xbuf..ctxb region:
  unsigned short* Abf = (unsigned short*)xbuf;       // 160000*512 ushorts = 40.96M floats
  float* sbuf = xbuf + 40960000;                     // 160000 floats
  unsigned short* w1T = (unsigned short*)(xbuf + 41120000);  // 131072 ushorts

  // 1) DAG embedding -> dict_matrix (bf16 MFMA pipeline)
  hipMemsetAsync(sbuf, 0, Rc * sizeof(float), stream);
  prep_w1T<<<512, 256, 0, stream>>>(attn_w1, w1T);
  build_A<<<Rc / 4, 256, 0, stream>>>(dx_leaves, dx_anc, dx_masks,
                                      embed_init_w, Abf);
  mlp_gemm<<<dim3(2, Rc / 128), 256, 0, stream>>>(Abf, w1T, attn_b1, attn_w2,
                                                  sbuf);
  dag_finalize<<<Cc, 256, 0, stream>>>(sbuf, dx_masks, dx_anc, attn_b2,
                                       embed_init_w, dict);

  auto run_encoder = [&](const float* wq, const float* wk, const float* wv,
                         const float* wo, const float* fw1, const float* fb1,
                         const float* fw2, const float* fb2, float* final_out) {
    gemm64<<<dim3(4, 512), 256, 0, stream>>>(xbuf, wq, nullptr, nullptr, qb,
                                             Mc, Hc, Hc, 0);
    gemm64<<<dim3(4, 512), 256, 0, stream>>>(xbuf, wk, nullptr, nullptr, kb,
                                             Mc, Hc, Hc, 0);
    gemm64<<<dim3(4, 512), 256, 0, stream>>>(xbuf, wv, nullptr, nullptr, vb,
                                             Mc, Hc, Hc, 0);
    attn_kernel<<<Bc * NHc, 256, 0, stream>>>(qb, kb, vb, code_mask, ctxb);
    gemm64<<<dim3(4, 512), 256, 0, stream>>>(ctxb, wo, nullptr, xbuf, xbuf,
                                             Mc, Hc, Hc, 0);
    for (int c4 = 0; c4 < 4; ++c4) {
      float* xc = xbuf + (size_t)c4 * 8192 * 256;
      float* oc = final_out + (size_t)c4 * 8192 * 256;
      gemm64<<<dim3(16, 128), 256, 0, stream>>>(xc, fw1, fb1, nullptr, hid,
                                                8192, FFc, Hc, 1);
      gemm64<<<dim3(4, 128), 256, 0, stream>>>(hid, fw2, fb2, xc, oc,
                                               8192, Hc, FFc, 0);
    }
  };

  // 2) visit stream
  gather_rows_f4<<<8192, 256, 0, stream>>>(input_ids,
                                           (const float4*)embed_inputs_w,
                                           (float4*)xbuf);
  run_encoder((const float*)d_in[13], (const float*)d_in[14],
              (const float*)d_in[15], (const float*)d_in[16],
              (const float*)d_in[17], (const float*)d_in[18],
              (const float*)d_in[19], (const float*)d_in[20], out);

  // 3) dag stream
  gather_rows_f4<<<8192, 256, 0, stream>>>(input_ids, (const float4*)dict,
                                           (float4*)xbuf);
  run_encoder((const float*)d_in[21], (const float*)d_in[22],
              (const float*)d_in[23], (const float*)d_in[24],
              (const float*)d_in[25], (const float*)d_in[26],
              (const float*)d_in[27], (const float*)d_in[28], xbuf);

  pool_kernel<<<Bc, 256, 0, stream>>>(xbuf, code_mask, pool_w, pool_b,
                                      out + 8388608);
}

// Round 3
// 1320.527 us; speedup vs baseline: 2.5366x; 1.9408x over previous
//
#include <hip/hip_runtime.h>
#include <hip/hip_bf16.h>
#include <math.h>

#define VERY_NEG (-1e30f)

// B=128, S=256, H=256, C=20000, NODES=25000, A=8, NH=8, d=32, FF=1024
constexpr int Bc = 128, Sc = 256, Hc = 256, Cc = 20000, Ac = 8, NHc = 8, DHc = 32, FFc = 1024;
constexpr int Mc = Bc * Sc;  // 32768 rows
constexpr int Rc = Cc * Ac;  // 160000 dag rows

typedef __attribute__((ext_vector_type(8))) short short8;
typedef __attribute__((ext_vector_type(4))) float floatx4;

static __device__ __forceinline__ unsigned short f2bf(float f) {
  union { float f; unsigned u; } v; v.f = f;
  unsigned r = v.u + 0x7FFF + ((v.u >> 16) & 1);   // RNE
  return (unsigned short)(r >> 16);
}
static __device__ __forceinline__ unsigned pack2(float lo, float hi) {
  return (unsigned)f2bf(lo) | ((unsigned)f2bf(hi) << 16);
}

// ---------------------------------------------------------------------------
// fp32 -> bf16 bulk convert (8 elems/thread)
// ---------------------------------------------------------------------------
__global__ __launch_bounds__(256) void convert_bf16(
    const float* __restrict__ in, unsigned short* __restrict__ out) {
  int gid = blockIdx.x * 256 + threadIdx.x;
  const float4* p = (const float4*)(in + (size_t)gid * 8);
  float4 a = p[0], b = p[1];
  uint4 o;
  o.x = pack2(a.x, a.y); o.y = pack2(a.z, a.w);
  o.z = pack2(b.x, b.y); o.w = pack2(b.z, b.w);
  *(uint4*)(out + (size_t)gid * 8) = o;
}

// ---------------------------------------------------------------------------
// Weight prep: W[K,N] fp32 -> Wt[N,K] bf16.  Klog2 = log2(K).
// ---------------------------------------------------------------------------
__global__ __launch_bounds__(256) void transpose_bf16(
    const float* __restrict__ w, unsigned short* __restrict__ wT, int Klog2,
    int N) {
  int gid = blockIdx.x * 256 + threadIdx.x;
  int K = 1 << Klog2;
  int k = gid & (K - 1);
  int n = gid >> Klog2;
  wT[gid] = f2bf(w[(size_t)k * N + n]);
}

// ---------------------------------------------------------------------------
// bf16 MFMA GEMM: C[M,N] = A[M,K] @ Bt[N,K]^T  (+bias)(relu)(+fp32 resid)
// 128x128 tile, 4 waves (2x2 of 64x64), 16x16x32 MFMA, BK=32, LDS pad +8.
// Grid: (N/128, M/128). Layout conventions HW-verified in round 1.
// ---------------------------------------------------------------------------
template <bool BIAS, bool RELU, bool RESID, bool OUTBF>
__global__ __launch_bounds__(256) void gemm_mfma(
    const unsigned short* __restrict__ A, const unsigned short* __restrict__ Bt,
    const float* __restrict__ bias, const float* __restrict__ resid,
    void* __restrict__ Cv, int N, int K) {
  __shared__ unsigned short As[128][40];
  __shared__ unsigned short Bs[128][40];
  const int tid = threadIdx.x;
  const int rowBase = blockIdx.y * 128;
  const int colBase = blockIdx.x * 128;
  const int wave = tid >> 6, lane = tid & 63;
  const int wm = wave >> 1, wn = wave & 1;
  const int quad = lane >> 4, l15 = lane & 15;
  const int r0 = tid >> 2, seg = tid & 3;

  floatx4 acc[4][4];
#pragma unroll
  for (int mt = 0; mt < 4; ++mt)
#pragma unroll
    for (int nt = 0; nt < 4; ++nt) acc[mt][nt] = (floatx4){0.f, 0.f, 0.f, 0.f};

  for (int k0 = 0; k0 < K; k0 += 32) {
#pragma unroll
    for (int it = 0; it < 2; ++it) {
      int r = r0 + it * 64;
      *(uint4*)&As[r][seg * 8] =
          *(const uint4*)(A + (size_t)(rowBase + r) * K + k0 + seg * 8);
      *(uint4*)&Bs[r][seg * 8] =
          *(const uint4*)(Bt + (size_t)(colBase + r) * K + k0 + seg * 8);
    }
    __syncthreads();
    short8 af[4], bfr[4];
#pragma unroll
    for (int mt = 0; mt < 4; ++mt)
      af[mt] = *(const short8*)&As[wm * 64 + mt * 16 + l15][quad * 8];
#pragma unroll
    for (int nt = 0; nt < 4; ++nt)
      bfr[nt] = *(const short8*)&Bs[wn * 64 + nt * 16 + l15][quad * 8];
#pragma unroll
    for (int mt = 0; mt < 4; ++mt)
#pragma unroll
      for (int nt = 0; nt < 4; ++nt)
        acc[mt][nt] = __builtin_amdgcn_mfma_f32_16x16x32_bf16(
            af[mt], bfr[nt], acc[mt][nt], 0, 0, 0);
    __syncthreads();
  }

#pragma unroll
  for (int mt = 0; mt < 4; ++mt) {
#pragma unroll
    for (int nt = 0; nt < 4; ++nt) {
      int col = colBase + wn * 64 + nt * 16 + l15;
      float bz = BIAS ? bias[col] : 0.f;
#pragma unroll
      for (int i = 0; i < 4; ++i) {
        int row = rowBase + wm * 64 + mt * 16 + quad * 4 + i;
        float v = acc[mt][nt][i];
        if (BIAS) v += bz;
        if (RELU) v = fmaxf(v, 0.f);
        if (RESID) v += resid[(size_t)row * N + col];
        if (OUTBF)
          ((unsigned short*)Cv)[(size_t)row * N + col] = f2bf(v);
        else
          ((float*)Cv)[(size_t)row * N + col] = v;
      }
    }
  }
}

// ---------------------------------------------------------------------------
// DAG stage 0: w1 [512,256] fp32 -> w1T [256,512] bf16
// ---------------------------------------------------------------------------
__global__ __launch_bounds__(256) void prep_w1T(const float* __restrict__ w1,
                                                unsigned short* __restrict__ w1T) {
  int gid = blockIdx.x * 256 + threadIdx.x;
  int n = gid >> 9, k = gid & 511;
  w1T[(size_t)n * 512 + k] = f2bf(w1[(size_t)k * 256 + n]);
}

// ---------------------------------------------------------------------------
// DAG stage 1: A [160000, 512] bf16 = concat(leaves_emb*m, anc_emb*m)
// ---------------------------------------------------------------------------
__global__ __launch_bounds__(256) void build_A(
    const int* __restrict__ leaves, const int* __restrict__ anc,
    const float* __restrict__ masks, const float* __restrict__ emb,
    unsigned short* __restrict__ A) {
  int t = threadIdx.x;
  int row = blockIdx.x * 4 + (t >> 6);
  int lane = t & 63;
  int node = (lane < 32) ? leaves[row] : anc[row];
  float m = masks[row];
  int col = (lane & 31) * 8;
  const float* src = emb + (size_t)node * 256 + col;
  float4 a = ((const float4*)src)[0];
  float4 b = ((const float4*)src)[1];
  uint4 o;
  o.x = pack2(a.x * m, a.y * m);
  o.y = pack2(a.z * m, a.w * m);
  o.z = pack2(b.x * m, b.y * m);
  o.w = pack2(b.z * m, b.w * m);
  *(uint4*)(A + (size_t)row * 512 + lane * 8) = o;
}

// ---------------------------------------------------------------------------
// DAG stage 2: [160000,512]@[512,256] MFMA + fused relu().w2 epilogue
// ---------------------------------------------------------------------------
__global__ __launch_bounds__(256) void mlp_gemm(
    const unsigned short* __restrict__ A, const unsigned short* __restrict__ Bt,
    const float* __restrict__ b1, const float* __restrict__ w2,
    float* __restrict__ s) {
  __shared__ unsigned short As[128][40];
  __shared__ unsigned short Bs[128][40];
  const int tid = threadIdx.x;
  const int rowBase = blockIdx.y * 128;
  const int colBase = blockIdx.x * 128;
  const int wave = tid >> 6, lane = tid & 63;
  const int wm = wave >> 1, wn = wave & 1;
  const int quad = lane >> 4, l15 = lane & 15;
  const int r0 = tid >> 2, seg = tid & 3;

  floatx4 acc[4][4];
#pragma unroll
  for (int mt = 0; mt < 4; ++mt)
#pragma unroll
    for (int nt = 0; nt < 4; ++nt) acc[mt][nt] = (floatx4){0.f, 0.f, 0.f, 0.f};

  for (int k0 = 0; k0 < 512; k0 += 32) {
#pragma unroll
    for (int it = 0; it < 2; ++it) {
      int r = r0 + it * 64;
      *(uint4*)&As[r][seg * 8] =
          *(const uint4*)(A + (size_t)(rowBase + r) * 512 + k0 + seg * 8);
      *(uint4*)&Bs[r][seg * 8] =
          *(const uint4*)(Bt + (size_t)(colBase + r) * 512 + k0 + seg * 8);
    }
    __syncthreads();
    short8 af[4], bfr[4];
#pragma unroll
    for (int mt = 0; mt < 4; ++mt)
      af[mt] = *(const short8*)&As[wm * 64 + mt * 16 + l15][quad * 8];
#pragma unroll
    for (int nt = 0; nt < 4; ++nt)
      bfr[nt] = *(const short8*)&Bs[wn * 64 + nt * 16 + l15][quad * 8];
#pragma unroll
    for (int mt = 0; mt < 4; ++mt)
#pragma unroll
      for (int nt = 0; nt < 4; ++nt)
        acc[mt][nt] = __builtin_amdgcn_mfma_f32_16x16x32_bf16(
            af[mt], bfr[nt], acc[mt][nt], 0, 0, 0);
    __syncthreads();
  }

  float b1c[4], w2c[4];
#pragma unroll
  for (int nt = 0; nt < 4; ++nt) {
    int col = colBase + wn * 64 + nt * 16 + l15;
    b1c[nt] = b1[col];
    w2c[nt] = w2[col];
  }
#pragma unroll
  for (int mt = 0; mt < 4; ++mt) {
#pragma unroll
    for (int i = 0; i < 4; ++i) {
      float p = 0.f;
#pragma unroll
      for (int nt = 0; nt < 4; ++nt) {
        float v = acc[mt][nt][i] + b1c[nt];
        p += fmaxf(v, 0.f) * w2c[nt];
      }
      p += __shfl_xor(p, 1, 64);
      p += __shfl_xor(p, 2, 64);
      p += __shfl_xor(p, 4, 64);
      p += __shfl_xor(p, 8, 64);
      if (l15 == 0)
        atomicAdd(s + rowBase + wm * 64 + mt * 16 + quad * 4 + i, p);
    }
  }
}

// ---------------------------------------------------------------------------
// DAG stage 3: softmax over A=8 + masked ancestor weighted sum -> dict.
// ---------------------------------------------------------------------------
__global__ __launch_bounds__(256) void dag_finalize(
    const float* __restrict__ s, const float* __restrict__ masks,
    const int* __restrict__ anc, const float* __restrict__ b2,
    const float* __restrict__ emb, float* __restrict__ dict) {
  const int c = blockIdx.x;
  const int t = threadIdx.x;
  __shared__ float sv[8], mv[8];
  __shared__ int nv[8];
  if (t < 8) {
    float m = masks[c * 8 + t];
    sv[t] = s[c * 8 + t] + b2[0] + (1.f - m) * VERY_NEG;
    mv[t] = m;
    nv[t] = anc[c * 8 + t];
  }
  __syncthreads();
  float mx = -INFINITY;
#pragma unroll
  for (int a = 0; a < 8; ++a) mx = fmaxf(mx, sv[a]);
  float e[8], sum = 0.f;
#pragma unroll
  for (int a = 0; a < 8; ++a) { e[a] = __expf(sv[a] - mx); sum += e[a]; }
  float inv = 1.f / sum;
  float o = 0.f;
#pragma unroll
  for (int a = 0; a < 8; ++a)
    o += e[a] * inv * mv[a] * emb[(size_t)nv[a] * 256 + t];
  dict[(size_t)(c + 1) * 256 + t] = o;
  if (c == 0) dict[t] = 0.f;
}

// ---------------------------------------------------------------------------
// Row gather (embedding lookup), float4-vectorized.
// ---------------------------------------------------------------------------
__global__ __launch_bounds__(256) void gather_rows_f4(
    const int* __restrict__ ids, const float4* __restrict__ table,
    float4* __restrict__ out) {
  int gid = blockIdx.x * 256 + threadIdx.x;
  int row = gid >> 6;
  int c4 = gid & 63;
  out[gid] = table[(size_t)ids[row] * 64 + c4];
}

// ---------------------------------------------------------------------------
// Fused per-(b,h) attention. 1024 blocks, 256 thr. (fp32, unchanged)
// ---------------------------------------------------------------------------
__global__ __launch_bounds__(256) void attn_kernel(
    const float* __restrict__ q, const float* __restrict__ k,
    const float* __restrict__ v, const float* __restrict__ code_mask,
    float* __restrict__ ctx) {
  const int b = blockIdx.x >> 3;
  const int h = blockIdx.x & 7;
  const int tid = threadIdx.x;
  __shared__ float Ks[256][32];
  __shared__ float Vs[256][32];
  __shared__ float madd[256];
  const size_t base = ((size_t)b * 256) * 256 + h * 32;

#pragma unroll
  for (int it = 0; it < 8; ++it) {
    int idx = tid + it * 256;
    int r = idx >> 3, d4 = (idx & 7) * 4;
    *(float4*)&Ks[r][d4] = *(const float4*)(k + base + (size_t)r * 256 + d4);
    *(float4*)&Vs[r][d4] = *(const float4*)(v + base + (size_t)r * 256 + d4);
  }
  madd[tid] = (1.f - code_mask[b * 256 + tid]) * VERY_NEG;
  __syncthreads();

  float4 qr[8];
#pragma unroll
  for (int d4 = 0; d4 < 8; ++d4)
    qr[d4] = *(const float4*)(q + base + (size_t)tid * 256 + d4 * 4);

  const float scale = 0.17677669529663687f;  // 1/sqrt(32)

  float mx = -INFINITY;
  for (int kk = 0; kk < 256; ++kk) {
    float s = 0.f;
#pragma unroll
    for (int d4 = 0; d4 < 8; ++d4) {
      float4 kv = *(const float4*)&Ks[kk][d4 * 4];
      s += qr[d4].x * kv.x + qr[d4].y * kv.y + qr[d4].z * kv.z + qr[d4].w * kv.w;
    }
    s = s * scale + madd[kk];
    mx = fmaxf(mx, s);
  }

  float4 acc[8];
#pragma unroll
  for (int d4 = 0; d4 < 8; ++d4) { acc[d4].x = 0; acc[d4].y = 0; acc[d4].z = 0; acc[d4].w = 0; }
  float l = 0.f;
  for (int kk = 0; kk < 256; ++kk) {
    float s = 0.f;
#pragma unroll
    for (int d4 = 0; d4 < 8; ++d4) {
      float4 kv = *(const float4*)&Ks[kk][d4 * 4];
      s += qr[d4].x * kv.x + qr[d4].y * kv.y + qr[d4].z * kv.z + qr[d4].w * kv.w;
    }
    s = s * scale + madd[kk];
    float w = __expf(s - mx);
    l += w;
#pragma unroll
    for (int d4 = 0; d4 < 8; ++d4) {
      float4 vv = *(const float4*)&Vs[kk][d4 * 4];
      acc[d4].x += w * vv.x; acc[d4].y += w * vv.y;
      acc[d4].z += w * vv.z; acc[d4].w += w * vv.w;
    }
  }
  float inv = 1.f / l;
#pragma unroll
  for (int d4 = 0; d4 < 8; ++d4) {
    float4 o;
    o.x = acc[d4].x * inv; o.y = acc[d4].y * inv;
    o.z = acc[d4].z * inv; o.w = acc[d4].w * inv;
    *(float4*)(ctx + base + (size_t)tid * 256 + d4 * 4) = o;
  }
}

// ---------------------------------------------------------------------------
// Attention pooling. 128 blocks (one per batch), 256 thr.
// ---------------------------------------------------------------------------
__global__ __launch_bounds__(256) void pool_kernel(
    const float* __restrict__ x, const float* __restrict__ code_mask,
    const float* __restrict__ pw, const float* __restrict__ pb,
    float* __restrict__ out) {
  const int b = blockIdx.x;
  const int t = threadIdx.x;
  __shared__ float ss[256];
  __shared__ float red[256];
  __shared__ float als[256];
  const float* xb = x + (size_t)b * 256 * 256;

  float s = pb[0];
  for (int j = 0; j < 256; j += 4) {
    float4 xv = *(const float4*)(xb + (size_t)t * 256 + j);
    float4 wv = *(const float4*)(pw + j);
    s += xv.x * wv.x + xv.y * wv.y + xv.z * wv.z + xv.w * wv.w;
  }
  s += (1.f - code_mask[b * 256 + t]) * VERY_NEG;
  ss[t] = s; red[t] = s;
  __syncthreads();
  for (int off = 128; off > 0; off >>= 1) {
    if (t < off) red[t] = fmaxf(red[t], red[t + off]);
    __syncthreads();
  }
  float m = red[0];
  __syncthreads();
  float e = __expf(ss[t] - m);
  als[t] = e; red[t] = e;
  __syncthreads();
  for (int off = 128; off > 0; off >>= 1) {
    if (t < off) red[t] += red[t + off];
    __syncthreads();
  }
  float inv = 1.f / red[0];
  float o = 0.f;
  for (int si = 0; si < 256; ++si) o += als[si] * xb[(size_t)si * 256 + t];
  out[b * 256 + t] = o * inv;
}

// ---------------------------------------------------------------------------
extern "C" void kernel_launch(void* const* d_in, const int* in_sizes, int n_in,
                              void* d_out, int out_size, void* d_ws,
                              size_t ws_size, hipStream_t stream) {
  const int* input_ids = (const int*)d_in[0];
  const float* code_mask = (const float*)d_in[1];
  const int* dx_leaves = (const int*)d_in[2];
  const int* dx_anc = (const int*)d_in[3];
  const float* dx_masks = (const float*)d_in[4];
  const float* embed_init_w = (const float*)d_in[5];
  const float* embed_inputs_w = (const float*)d_in[6];
  const float* attn_w1 = (const float*)d_in[7];
  const float* attn_b1 = (const float*)d_in[8];
  const float* attn_w2 = (const float*)d_in[9];
  const float* attn_b2 = (const float*)d_in[10];
  const float* pool_w = (const float*)d_in[11];
  const float* pool_b = (const float*)d_in[12];

  float* out = (float*)d_out;
  float* ws = (float*)d_ws;

  // workspace layout (floats)
  float* dict = ws;                      // 5,120,256
  float* xbuf = dict + 5120256;          // 8,388,608
  float* qb   = xbuf + 8388608;          // 8,388,608
  float* kb   = qb + 8388608;            // 8,388,608
  float* vb   = kb + 8388608;            // 8,388,608
  float* ctxb = vb + 8388608;            // 8,388,608
  float* wend = ctxb + 8388608;          // weight area: 393,216 floats

  // DAG-phase aliases over the (currently dead) xbuf..ctxb region:
  unsigned short* Abf = (unsigned short*)xbuf;
  float* sbuf = xbuf + 40960000;
  unsigned short* w1T_dag = (unsigned short*)(xbuf + 41120000);

  // encoder-phase aliases:
  unsigned short* xbb = (unsigned short*)ctxb;  // bf16(x): alive only pre-attn / post-WO
  unsigned short* cbb = (unsigned short*)qb;    // bf16(ctx): alive only during WO
  unsigned short* hid = (unsigned short*)kb;    // bf16 FFN hidden chunk [16384,1024]
  // bf16 weights (persist across one layer):
  unsigned short* wqT  = (unsigned short*)wend;         // 65,536
  unsigned short* wkT  = wqT + 65536;
  unsigned short* wvT  = wkT + 65536;
  unsigned short* woT  = wvT + 65536;
  unsigned short* fw1T = woT + 65536;                   // 262,144
  unsigned short* fw2T = fw1T + 262144;                 // 262,144

  // 1) DAG embedding -> dict_matrix (bf16 MFMA pipeline)
  hipMemsetAsync(sbuf, 0, Rc * sizeof(float), stream);
  prep_w1T<<<512, 256, 0, stream>>>(attn_w1, w1T_dag);
  build_A<<<Rc / 4, 256, 0, stream>>>(dx_leaves, dx_anc, dx_masks,
                                      embed_init_w, Abf);
  mlp_gemm<<<dim3(2, Rc / 128), 256, 0, stream>>>(Abf, w1T_dag, attn_b1,
                                                  attn_w2, sbuf);
  dag_finalize<<<Cc, 256, 0, stream>>>(sbuf, dx_masks, dx_anc, attn_b2,
                                       embed_init_w, dict);

  auto run_encoder = [&](const float* wq, const float* wk, const float* wv,
                         const float* wo, const float* fw1, const float* fb1,
                         const float* fw2, const float* fb2, float* final_out) {
    // per-layer weight prep (bf16, transposed)
    transpose_bf16<<<256, 256, 0, stream>>>(wq, wqT, 8, 256);
    transpose_bf16<<<256, 256, 0, stream>>>(wk, wkT, 8, 256);
    transpose_bf16<<<256, 256, 0, stream>>>(wv, wvT, 8, 256);
    transpose_bf16<<<256, 256, 0, stream>>>(wo, woT, 8, 256);
    transpose_bf16<<<1024, 256, 0, stream>>>(fw1, fw1T, 8, 1024);  // [1024][256]
    transpose_bf16<<<1024, 256, 0, stream>>>(fw2, fw2T, 10, 256);  // [256][1024]

    // xb = bf16(x)
    convert_bf16<<<4096, 256, 0, stream>>>(xbuf, xbb);
    // QKV (fp32 out)
    gemm_mfma<false, false, false, false><<<dim3(2, 256), 256, 0, stream>>>(
        xbb, wqT, nullptr, nullptr, qb, 256, 256);
    gemm_mfma<false, false, false, false><<<dim3(2, 256), 256, 0, stream>>>(
        xbb, wkT, nullptr, nullptr, kb, 256, 256);
    gemm_mfma<false, false, false, false><<<dim3(2, 256), 256, 0, stream>>>(
        xbb, wvT, nullptr, nullptr, vb, 256, 256);
    // attention -> ctx (overwrites xbb region; xbb is dead now)
    attn_kernel<<<Bc * NHc, 256, 0, stream>>>(qb, kb, vb, code_mask, ctxb);
    // cb = bf16(ctx) into dead q; x += cb @ woT
    convert_bf16<<<4096, 256, 0, stream>>>(ctxb, cbb);
    gemm_mfma<false, false, true, false><<<dim3(2, 256), 256, 0, stream>>>(
        cbb, woT, nullptr, xbuf, xbuf, 256, 256);
    // xb2 = bf16(x) into dead ctx region
    convert_bf16<<<4096, 256, 0, stream>>>(xbuf, xbb);
    // FFN in 2 row-chunks of 16384; hidden stored bf16 in dead k-buffer
    for (int ch = 0; ch < 2; ++ch) {
      const unsigned short* xc = xbb + (size_t)ch * 16384 * 256;
      float* rc = xbuf + (size_t)ch * 16384 * 256;
      float* oc = final_out + (size_t)ch * 16384 * 256;
      gemm_mfma<true, true, false, true><<<dim3(8, 128), 256, 0, stream>>>(
          xc, fw1T, fb1, nullptr, hid, 1024, 256);
      gemm_mfma<true, false, true, false><<<dim3(2, 128), 256, 0, stream>>>(
          hid, fw2T, fb2, rc, oc, 256, 1024);
    }
  };

  // 2) visit stream
  gather_rows_f4<<<8192, 256, 0, stream>>>(input_ids,
                                           (const float4*)embed_inputs_w,
                                           (float4*)xbuf);
  run_encoder((const float*)d_in[13], (const float*)d_in[14],
              (const float*)d_in[15], (const float*)d_in[16],
              (const float*)d_in[17], (const float*)d_in[18],
              (const float*)d_in[19], (const float*)d_in[20], out);

  // 3) dag stream
  gather_rows_f4<<<8192, 256, 0, stream>>>(input_ids, (const float4*)dict,
                                           (float4*)xbuf);
  run_encoder((const float*)d_in[21], (const float*)d_in[22],
              (const float*)d_in[23], (const float*)d_in[24],
              (const float*)d_in[25], (const float*)d_in[26],
              (const float*)d_in[27], (const float*)d_in[28], xbuf);

  pool_kernel<<<Bc, 256, 0, stream>>>(xbuf, code_mask, pool_w, pool_b,
                                      out + 8388608);
}

// Round 4
// 856.281 us; speedup vs baseline: 3.9118x; 1.5422x over previous
//
#include <hip/hip_runtime.h>
#include <hip/hip_bf16.h>
#include <math.h>

#define VERY_NEG (-1e30f)

// B=128, S=256, H=256, C=20000, NODES=25000, A=8, NH=8, d=32, FF=1024
constexpr int Bc = 128, Sc = 256, Hc = 256, Cc = 20000, Ac = 8, NHc = 8, DHc = 32, FFc = 1024;
constexpr int Mc = Bc * Sc;  // 32768 rows
constexpr int Rc = Cc * Ac;  // 160000 dag rows

typedef __attribute__((ext_vector_type(8))) short short8;
typedef __attribute__((ext_vector_type(4))) float floatx4;

static __device__ __forceinline__ unsigned short f2bf(float f) {
  union { float f; unsigned u; } v; v.f = f;
  unsigned r = v.u + 0x7FFF + ((v.u >> 16) & 1);   // RNE
  return (unsigned short)(r >> 16);
}
static __device__ __forceinline__ unsigned pack2(float lo, float hi) {
  return (unsigned)f2bf(lo) | ((unsigned)f2bf(hi) << 16);
}

// ---------------------------------------------------------------------------
// fp32 -> bf16 bulk convert (8 elems/thread)
// ---------------------------------------------------------------------------
__global__ __launch_bounds__(256) void convert_bf16(
    const float* __restrict__ in, unsigned short* __restrict__ out) {
  int gid = blockIdx.x * 256 + threadIdx.x;
  const float4* p = (const float4*)(in + (size_t)gid * 8);
  float4 a = p[0], b = p[1];
  uint4 o;
  o.x = pack2(a.x, a.y); o.y = pack2(a.z, a.w);
  o.z = pack2(b.x, b.y); o.w = pack2(b.z, b.w);
  *(uint4*)(out + (size_t)gid * 8) = o;
}

// ---------------------------------------------------------------------------
// Weight prep: W[K,N] fp32 -> Wt[N,K] bf16.  Klog2 = log2(K).
// ---------------------------------------------------------------------------
__global__ __launch_bounds__(256) void transpose_bf16(
    const float* __restrict__ w, unsigned short* __restrict__ wT, int Klog2,
    int N) {
  int gid = blockIdx.x * 256 + threadIdx.x;
  int K = 1 << Klog2;
  int k = gid & (K - 1);
  int n = gid >> Klog2;
  wT[gid] = f2bf(w[(size_t)k * N + n]);
}

// ---------------------------------------------------------------------------
// bf16 MFMA GEMM: C[M,N] = A[M,K] @ Bt[N,K]^T  (+bias)(relu)(+fp32 resid)
// 128x128 tile, 4 waves (2x2 of 64x64), 16x16x32 MFMA, BK=32, LDS pad +8.
// ---------------------------------------------------------------------------
template <bool BIAS, bool RELU, bool RESID, bool OUTBF>
__global__ __launch_bounds__(256) void gemm_mfma(
    const unsigned short* __restrict__ A, const unsigned short* __restrict__ Bt,
    const float* __restrict__ bias, const float* __restrict__ resid,
    void* __restrict__ Cv, int N, int K) {
  __shared__ unsigned short As[128][40];
  __shared__ unsigned short Bs[128][40];
  const int tid = threadIdx.x;
  const int rowBase = blockIdx.y * 128;
  const int colBase = blockIdx.x * 128;
  const int wave = tid >> 6, lane = tid & 63;
  const int wm = wave >> 1, wn = wave & 1;
  const int quad = lane >> 4, l15 = lane & 15;
  const int r0 = tid >> 2, seg = tid & 3;

  floatx4 acc[4][4];
#pragma unroll
  for (int mt = 0; mt < 4; ++mt)
#pragma unroll
    for (int nt = 0; nt < 4; ++nt) acc[mt][nt] = (floatx4){0.f, 0.f, 0.f, 0.f};

  for (int k0 = 0; k0 < K; k0 += 32) {
#pragma unroll
    for (int it = 0; it < 2; ++it) {
      int r = r0 + it * 64;
      *(uint4*)&As[r][seg * 8] =
          *(const uint4*)(A + (size_t)(rowBase + r) * K + k0 + seg * 8);
      *(uint4*)&Bs[r][seg * 8] =
          *(const uint4*)(Bt + (size_t)(colBase + r) * K + k0 + seg * 8);
    }
    __syncthreads();
    short8 af[4], bfr[4];
#pragma unroll
    for (int mt = 0; mt < 4; ++mt)
      af[mt] = *(const short8*)&As[wm * 64 + mt * 16 + l15][quad * 8];
#pragma unroll
    for (int nt = 0; nt < 4; ++nt)
      bfr[nt] = *(const short8*)&Bs[wn * 64 + nt * 16 + l15][quad * 8];
#pragma unroll
    for (int mt = 0; mt < 4; ++mt)
#pragma unroll
      for (int nt = 0; nt < 4; ++nt)
        acc[mt][nt] = __builtin_amdgcn_mfma_f32_16x16x32_bf16(
            af[mt], bfr[nt], acc[mt][nt], 0, 0, 0);
    __syncthreads();
  }

#pragma unroll
  for (int mt = 0; mt < 4; ++mt) {
#pragma unroll
    for (int nt = 0; nt < 4; ++nt) {
      int col = colBase + wn * 64 + nt * 16 + l15;
      float bz = BIAS ? bias[col] : 0.f;
#pragma unroll
      for (int i = 0; i < 4; ++i) {
        int row = rowBase + wm * 64 + mt * 16 + quad * 4 + i;
        float v = acc[mt][nt][i];
        if (BIAS) v += bz;
        if (RELU) v = fmaxf(v, 0.f);
        if (RESID) v += resid[(size_t)row * N + col];
        if (OUTBF)
          ((unsigned short*)Cv)[(size_t)row * N + col] = f2bf(v);
        else
          ((float*)Cv)[(size_t)row * N + col] = v;
      }
    }
  }
}

// ---------------------------------------------------------------------------
// DAG stage 0: w1 [512,256] fp32 -> w1T [256,512] bf16
// ---------------------------------------------------------------------------
__global__ __launch_bounds__(256) void prep_w1T(const float* __restrict__ w1,
                                                unsigned short* __restrict__ w1T) {
  int gid = blockIdx.x * 256 + threadIdx.x;
  int n = gid >> 9, k = gid & 511;
  w1T[(size_t)n * 512 + k] = f2bf(w1[(size_t)k * 256 + n]);
}

// ---------------------------------------------------------------------------
// DAG stage 1: A [160000, 512] bf16 = concat(leaves_emb*m, anc_emb*m)
// ---------------------------------------------------------------------------
__global__ __launch_bounds__(256) void build_A(
    const int* __restrict__ leaves, const int* __restrict__ anc,
    const float* __restrict__ masks, const float* __restrict__ emb,
    unsigned short* __restrict__ A) {
  int t = threadIdx.x;
  int row = blockIdx.x * 4 + (t >> 6);
  int lane = t & 63;
  int node = (lane < 32) ? leaves[row] : anc[row];
  float m = masks[row];
  int col = (lane & 31) * 8;
  const float* src = emb + (size_t)node * 256 + col;
  float4 a = ((const float4*)src)[0];
  float4 b = ((const float4*)src)[1];
  uint4 o;
  o.x = pack2(a.x * m, a.y * m);
  o.y = pack2(a.z * m, a.w * m);
  o.z = pack2(b.x * m, b.y * m);
  o.w = pack2(b.z * m, b.w * m);
  *(uint4*)(A + (size_t)row * 512 + lane * 8) = o;
}

// ---------------------------------------------------------------------------
// DAG stage 2: [160000,512]@[512,256] MFMA + fused relu().w2 epilogue
// ---------------------------------------------------------------------------
__global__ __launch_bounds__(256) void mlp_gemm(
    const unsigned short* __restrict__ A, const unsigned short* __restrict__ Bt,
    const float* __restrict__ b1, const float* __restrict__ w2,
    float* __restrict__ s) {
  __shared__ unsigned short As[128][40];
  __shared__ unsigned short Bs[128][40];
  const int tid = threadIdx.x;
  const int rowBase = blockIdx.y * 128;
  const int colBase = blockIdx.x * 128;
  const int wave = tid >> 6, lane = tid & 63;
  const int wm = wave >> 1, wn = wave & 1;
  const int quad = lane >> 4, l15 = lane & 15;
  const int r0 = tid >> 2, seg = tid & 3;

  floatx4 acc[4][4];
#pragma unroll
  for (int mt = 0; mt < 4; ++mt)
#pragma unroll
    for (int nt = 0; nt < 4; ++nt) acc[mt][nt] = (floatx4){0.f, 0.f, 0.f, 0.f};

  for (int k0 = 0; k0 < 512; k0 += 32) {
#pragma unroll
    for (int it = 0; it < 2; ++it) {
      int r = r0 + it * 64;
      *(uint4*)&As[r][seg * 8] =
          *(const uint4*)(A + (size_t)(rowBase + r) * 512 + k0 + seg * 8);
      *(uint4*)&Bs[r][seg * 8] =
          *(const uint4*)(Bt + (size_t)(colBase + r) * 512 + k0 + seg * 8);
    }
    __syncthreads();
    short8 af[4], bfr[4];
#pragma unroll
    for (int mt = 0; mt < 4; ++mt)
      af[mt] = *(const short8*)&As[wm * 64 + mt * 16 + l15][quad * 8];
#pragma unroll
    for (int nt = 0; nt < 4; ++nt)
      bfr[nt] = *(const short8*)&Bs[wn * 64 + nt * 16 + l15][quad * 8];
#pragma unroll
    for (int mt = 0; mt < 4; ++mt)
#pragma unroll
      for (int nt = 0; nt < 4; ++nt)
        acc[mt][nt] = __builtin_amdgcn_mfma_f32_16x16x32_bf16(
            af[mt], bfr[nt], acc[mt][nt], 0, 0, 0);
    __syncthreads();
  }

  float b1c[4], w2c[4];
#pragma unroll
  for (int nt = 0; nt < 4; ++nt) {
    int col = colBase + wn * 64 + nt * 16 + l15;
    b1c[nt] = b1[col];
    w2c[nt] = w2[col];
  }
#pragma unroll
  for (int mt = 0; mt < 4; ++mt) {
#pragma unroll
    for (int i = 0; i < 4; ++i) {
      float p = 0.f;
#pragma unroll
      for (int nt = 0; nt < 4; ++nt) {
        float v = acc[mt][nt][i] + b1c[nt];
        p += fmaxf(v, 0.f) * w2c[nt];
      }
      p += __shfl_xor(p, 1, 64);
      p += __shfl_xor(p, 2, 64);
      p += __shfl_xor(p, 4, 64);
      p += __shfl_xor(p, 8, 64);
      if (l15 == 0)
        atomicAdd(s + rowBase + wm * 64 + mt * 16 + quad * 4 + i, p);
    }
  }
}

// ---------------------------------------------------------------------------
// DAG stage 3: softmax over A=8 + masked ancestor weighted sum -> dict.
// ---------------------------------------------------------------------------
__global__ __launch_bounds__(256) void dag_finalize(
    const float* __restrict__ s, const float* __restrict__ masks,
    const int* __restrict__ anc, const float* __restrict__ b2,
    const float* __restrict__ emb, float* __restrict__ dict) {
  const int c = blockIdx.x;
  const int t = threadIdx.x;
  __shared__ float sv[8], mv[8];
  __shared__ int nv[8];
  if (t < 8) {
    float m = masks[c * 8 + t];
    sv[t] = s[c * 8 + t] + b2[0] + (1.f - m) * VERY_NEG;
    mv[t] = m;
    nv[t] = anc[c * 8 + t];
  }
  __syncthreads();
  float mx = -INFINITY;
#pragma unroll
  for (int a = 0; a < 8; ++a) mx = fmaxf(mx, sv[a]);
  float e[8], sum = 0.f;
#pragma unroll
  for (int a = 0; a < 8; ++a) { e[a] = __expf(sv[a] - mx); sum += e[a]; }
  float inv = 1.f / sum;
  float o = 0.f;
#pragma unroll
  for (int a = 0; a < 8; ++a)
    o += e[a] * inv * mv[a] * emb[(size_t)nv[a] * 256 + t];
  dict[(size_t)(c + 1) * 256 + t] = o;
  if (c == 0) dict[t] = 0.f;
}

// ---------------------------------------------------------------------------
// Row gather (embedding lookup), float4-vectorized.
// ---------------------------------------------------------------------------
__global__ __launch_bounds__(256) void gather_rows_f4(
    const int* __restrict__ ids, const float4* __restrict__ table,
    float4* __restrict__ out) {
  int gid = blockIdx.x * 256 + threadIdx.x;
  int row = gid >> 6;
  int c4 = gid & 63;
  out[gid] = table[(size_t)ids[row] * 64 + c4];
}

// ---------------------------------------------------------------------------
// MFMA flash attention. One block per (b,h); 4 waves; wave owns 64 q-rows.
// q/k/v/ctx: bf16 [B*S][256], head h = cols h*32..h*32+31.
// Single pass over 4 k-tiles of 64 with online softmax. No barriers in loop
// (P buffers wave-private).
// ---------------------------------------------------------------------------
__global__ __launch_bounds__(256) void attn_mfma(
    const unsigned short* __restrict__ q, const unsigned short* __restrict__ k,
    const unsigned short* __restrict__ v, const float* __restrict__ cm,
    unsigned short* __restrict__ ctx) {
  __shared__ unsigned short Ks[256][40];   // [seq][d] pad->40 (16B-aligned rows)
  __shared__ unsigned short Vt[32][264];   // [d][seq] pad->264
  __shared__ unsigned short Ps[4][64][72]; // wave-private P (also Vtmp/OsW reuse)
  __shared__ float madd[256];
  const int b = blockIdx.x >> 3, h = blockIdx.x & 7;
  const int tid = threadIdx.x;
  const int wave = tid >> 6, lane = tid & 63;
  const int quad = lane >> 4, l15 = lane & 15;
  const size_t tokbase = (size_t)b * 256;
  const int hoff = h * 32;

  unsigned short* Vtmp = &Ps[0][0][0];  // [256][40] staging

  // stage K, Vtmp (coalesced 64B segments), madd
#pragma unroll
  for (int it = 0; it < 4; ++it) {
    int idx = tid + it * 256;
    int row = idx >> 2, c = idx & 3;
    size_t g = (tokbase + row) * 256 + hoff + c * 8;
    *(uint4*)&Ks[row][c * 8] = *(const uint4*)(k + g);
    *(uint4*)(Vtmp + row * 40 + c * 8) = *(const uint4*)(v + g);
  }
  madd[tid] = (1.f - cm[b * 256 + tid]) * VERY_NEG;
  __syncthreads();
  // transpose Vtmp -> Vt (conflict-free b16 writes: 64 consecutive rows/wave)
#pragma unroll
  for (int it = 0; it < 4; ++it) {
    int idx = tid + it * 256;
    int row = idx & 255, c = idx >> 8;
    uint4 w = *(const uint4*)(Vtmp + row * 40 + c * 8);
    const unsigned short* wsp = (const unsigned short*)&w;
#pragma unroll
    for (int j = 0; j < 8; ++j) Vt[c * 8 + j][row] = wsp[j];
  }
  __syncthreads();

  // Q fragments in registers (A-layout: row=l15, k=quad*8+j)
  short8 qf[4];
#pragma unroll
  for (int mt = 0; mt < 4; ++mt) {
    size_t qrow = tokbase + wave * 64 + mt * 16 + l15;
    qf[mt] = *(const short8*)(q + qrow * 256 + hoff + quad * 8);
  }
  float madd_r[16];
#pragma unroll
  for (int nt = 0; nt < 16; ++nt) madd_r[nt] = madd[nt * 16 + l15];

  float m_r[4][4], l_r[4][4];
  floatx4 oa[4][2];
#pragma unroll
  for (int mt = 0; mt < 4; ++mt)
#pragma unroll
    for (int i = 0; i < 4; ++i) { m_r[mt][i] = -INFINITY; l_r[mt][i] = 0.f; }
#pragma unroll
  for (int mt = 0; mt < 4; ++mt)
#pragma unroll
    for (int nd = 0; nd < 2; ++nd) oa[mt][nd] = (floatx4){0.f, 0.f, 0.f, 0.f};

  const float scale = 0.17677669529663687f;  // 1/sqrt(32)

  for (int t = 0; t < 4; ++t) {
    // S = Q @ K^T  (K frag: B^T[n=seq][k=d] contiguous)
    short8 kf[4];
#pragma unroll
    for (int nt = 0; nt < 4; ++nt)
      kf[nt] = *(const short8*)&Ks[t * 64 + nt * 16 + l15][quad * 8];
    floatx4 sa[4][4];
#pragma unroll
    for (int mt = 0; mt < 4; ++mt)
#pragma unroll
      for (int nt = 0; nt < 4; ++nt) sa[mt][nt] = (floatx4){0.f, 0.f, 0.f, 0.f};
#pragma unroll
    for (int mt = 0; mt < 4; ++mt)
#pragma unroll
      for (int nt = 0; nt < 4; ++nt)
        sa[mt][nt] = __builtin_amdgcn_mfma_f32_16x16x32_bf16(
            qf[mt], kf[nt], sa[mt][nt], 0, 0, 0);

    // online softmax (C-layout: row=quad*4+i, col=l15)
#pragma unroll
    for (int mt = 0; mt < 4; ++mt) {
#pragma unroll
      for (int i = 0; i < 4; ++i) {
        float rmax = -INFINITY;
#pragma unroll
        for (int nt = 0; nt < 4; ++nt) {
          float sv = sa[mt][nt][i] * scale + madd_r[t * 4 + nt];
          sa[mt][nt][i] = sv;
          rmax = fmaxf(rmax, sv);
        }
        rmax = fmaxf(rmax, __shfl_xor(rmax, 1, 64));
        rmax = fmaxf(rmax, __shfl_xor(rmax, 2, 64));
        rmax = fmaxf(rmax, __shfl_xor(rmax, 4, 64));
        rmax = fmaxf(rmax, __shfl_xor(rmax, 8, 64));
        float mn = fmaxf(m_r[mt][i], rmax);
        float alpha = __expf(m_r[mt][i] - mn);
        m_r[mt][i] = mn;
        float rs = 0.f;
#pragma unroll
        for (int nt = 0; nt < 4; ++nt) {
          float p = __expf(sa[mt][nt][i] - mn);
          sa[mt][nt][i] = p;
          rs += p;
        }
        rs += __shfl_xor(rs, 1, 64);
        rs += __shfl_xor(rs, 2, 64);
        rs += __shfl_xor(rs, 4, 64);
        rs += __shfl_xor(rs, 8, 64);
        l_r[mt][i] = l_r[mt][i] * alpha + rs;
#pragma unroll
        for (int nd = 0; nd < 2; ++nd) oa[mt][nd][i] *= alpha;
      }
    }
    // P (bf16) -> wave-private LDS (C-layout -> A-layout transform)
#pragma unroll
    for (int mt = 0; mt < 4; ++mt)
#pragma unroll
      for (int nt = 0; nt < 4; ++nt)
#pragma unroll
        for (int i = 0; i < 4; ++i)
          Ps[wave][mt * 16 + quad * 4 + i][nt * 16 + l15] =
              f2bf(sa[mt][nt][i]);
    __asm__ __volatile__("s_waitcnt lgkmcnt(0)" ::: "memory");
    // O += P @ V   (A frag from Ps contiguous; B frag from Vt contiguous)
#pragma unroll
    for (int ks = 0; ks < 2; ++ks) {
      short8 vf[2];
#pragma unroll
      for (int nd = 0; nd < 2; ++nd)
        vf[nd] =
            *(const short8*)&Vt[nd * 16 + l15][t * 64 + ks * 32 + quad * 8];
#pragma unroll
      for (int mt = 0; mt < 4; ++mt) {
        short8 pf = *(const short8*)&Ps[wave][mt * 16 + l15][ks * 32 + quad * 8];
#pragma unroll
        for (int nd = 0; nd < 2; ++nd)
          oa[mt][nd] = __builtin_amdgcn_mfma_f32_16x16x32_bf16(
              pf, vf[nd], oa[mt][nd], 0, 0, 0);
      }
    }
    __asm__ __volatile__("s_waitcnt lgkmcnt(0)" ::: "memory");
  }

  // epilogue: O/l -> bf16 via LDS (reuse wave's Ps as [64][40]) -> coalesced
  unsigned short* OsW = &Ps[wave][0][0];
#pragma unroll
  for (int mt = 0; mt < 4; ++mt)
#pragma unroll
    for (int nd = 0; nd < 2; ++nd)
#pragma unroll
      for (int i = 0; i < 4; ++i)
        OsW[(mt * 16 + quad * 4 + i) * 40 + nd * 16 + l15] =
            f2bf(oa[mt][nd][i] / l_r[mt][i]);
  __asm__ __volatile__("s_waitcnt lgkmcnt(0)" ::: "memory");
#pragma unroll
  for (int it = 0; it < 4; ++it) {
    int idx = it * 64 + lane;
    int row = idx >> 2, c = idx & 3;
    uint4 w = *(const uint4*)(OsW + row * 40 + c * 8);
    *(uint4*)(ctx + (tokbase + wave * 64 + row) * 256 + hoff + c * 8) = w;
  }
}

// ---------------------------------------------------------------------------
// Attention pooling. 128 blocks (one per batch), 256 thr.
// ---------------------------------------------------------------------------
__global__ __launch_bounds__(256) void pool_kernel(
    const float* __restrict__ x, const float* __restrict__ code_mask,
    const float* __restrict__ pw, const float* __restrict__ pb,
    float* __restrict__ out) {
  const int b = blockIdx.x;
  const int t = threadIdx.x;
  __shared__ float ss[256];
  __shared__ float red[256];
  __shared__ float als[256];
  const float* xb = x + (size_t)b * 256 * 256;

  float s = pb[0];
  for (int j = 0; j < 256; j += 4) {
    float4 xv = *(const float4*)(xb + (size_t)t * 256 + j);
    float4 wv = *(const float4*)(pw + j);
    s += xv.x * wv.x + xv.y * wv.y + xv.z * wv.z + xv.w * wv.w;
  }
  s += (1.f - code_mask[b * 256 + t]) * VERY_NEG;
  ss[t] = s; red[t] = s;
  __syncthreads();
  for (int off = 128; off > 0; off >>= 1) {
    if (t < off) red[t] = fmaxf(red[t], red[t + off]);
    __syncthreads();
  }
  float m = red[0];
  __syncthreads();
  float e = __expf(ss[t] - m);
  als[t] = e; red[t] = e;
  __syncthreads();
  for (int off = 128; off > 0; off >>= 1) {
    if (t < off) red[t] += red[t + off];
    __syncthreads();
  }
  float inv = 1.f / red[0];
  float o = 0.f;
  for (int si = 0; si < 256; ++si) o += als[si] * xb[(size_t)si * 256 + t];
  out[b * 256 + t] = o * inv;
}

// ---------------------------------------------------------------------------
extern "C" void kernel_launch(void* const* d_in, const int* in_sizes, int n_in,
                              void* d_out, int out_size, void* d_ws,
                              size_t ws_size, hipStream_t stream) {
  const int* input_ids = (const int*)d_in[0];
  const float* code_mask = (const float*)d_in[1];
  const int* dx_leaves = (const int*)d_in[2];
  const int* dx_anc = (const int*)d_in[3];
  const float* dx_masks = (const float*)d_in[4];
  const float* embed_init_w = (const float*)d_in[5];
  const float* embed_inputs_w = (const float*)d_in[6];
  const float* attn_w1 = (const float*)d_in[7];
  const float* attn_b1 = (const float*)d_in[8];
  const float* attn_w2 = (const float*)d_in[9];
  const float* attn_b2 = (const float*)d_in[10];
  const float* pool_w = (const float*)d_in[11];
  const float* pool_b = (const float*)d_in[12];

  float* out = (float*)d_out;
  float* ws = (float*)d_ws;

  // workspace layout (floats)
  float* dict = ws;                      // 5,120,256
  float* xbuf = dict + 5120256;          // 8,388,608
  float* qb   = xbuf + 8388608;          // 8,388,608
  float* kb   = qb + 8388608;            // 8,388,608
  float* vb   = kb + 8388608;            // 8,388,608
  float* ctxb = vb + 8388608;            // 8,388,608
  float* wend = ctxb + 8388608;          // weight area

  // DAG-phase aliases over the (currently dead) xbuf..ctxb region:
  unsigned short* Abf = (unsigned short*)xbuf;
  float* sbuf = xbuf + 40960000;
  unsigned short* w1T_dag = (unsigned short*)(xbuf + 41120000);

  // encoder-phase aliases:
  unsigned short* xbb  = (unsigned short*)ctxb;  // bf16(x) / later bf16 ctx
  unsigned short* qb16 = (unsigned short*)qb;    // bf16 Q
  unsigned short* kb16 = (unsigned short*)kb;    // bf16 K
  unsigned short* vb16 = (unsigned short*)vb;    // bf16 V
  unsigned short* hid  = (unsigned short*)kb;    // bf16 FFN hidden [16384,1024]
  // bf16 weights:
  unsigned short* wqT  = (unsigned short*)wend;
  unsigned short* wkT  = wqT + 65536;
  unsigned short* wvT  = wkT + 65536;
  unsigned short* woT  = wvT + 65536;
  unsigned short* fw1T = woT + 65536;
  unsigned short* fw2T = fw1T + 262144;

  // 1) DAG embedding -> dict_matrix (bf16 MFMA pipeline)
  hipMemsetAsync(sbuf, 0, Rc * sizeof(float), stream);
  prep_w1T<<<512, 256, 0, stream>>>(attn_w1, w1T_dag);
  build_A<<<Rc / 4, 256, 0, stream>>>(dx_leaves, dx_anc, dx_masks,
                                      embed_init_w, Abf);
  mlp_gemm<<<dim3(2, Rc / 128), 256, 0, stream>>>(Abf, w1T_dag, attn_b1,
                                                  attn_w2, sbuf);
  dag_finalize<<<Cc, 256, 0, stream>>>(sbuf, dx_masks, dx_anc, attn_b2,
                                       embed_init_w, dict);

  auto run_encoder = [&](const float* wq, const float* wk, const float* wv,
                         const float* wo, const float* fw1, const float* fb1,
                         const float* fw2, const float* fb2, float* final_out) {
    transpose_bf16<<<256, 256, 0, stream>>>(wq, wqT, 8, 256);
    transpose_bf16<<<256, 256, 0, stream>>>(wk, wkT, 8, 256);
    transpose_bf16<<<256, 256, 0, stream>>>(wv, wvT, 8, 256);
    transpose_bf16<<<256, 256, 0, stream>>>(wo, woT, 8, 256);
    transpose_bf16<<<1024, 256, 0, stream>>>(fw1, fw1T, 8, 1024);
    transpose_bf16<<<1024, 256, 0, stream>>>(fw2, fw2T, 10, 256);

    // xb = bf16(x)
    convert_bf16<<<4096, 256, 0, stream>>>(xbuf, xbb);
    // QKV (bf16 out, feeds MFMA attention directly)
    gemm_mfma<false, false, false, true><<<dim3(2, 256), 256, 0, stream>>>(
        xbb, wqT, nullptr, nullptr, qb16, 256, 256);
    gemm_mfma<false, false, false, true><<<dim3(2, 256), 256, 0, stream>>>(
        xbb, wkT, nullptr, nullptr, kb16, 256, 256);
    gemm_mfma<false, false, false, true><<<dim3(2, 256), 256, 0, stream>>>(
        xbb, wvT, nullptr, nullptr, vb16, 256, 256);
    // MFMA flash attention -> bf16 ctx (into xbb region; xbb dead post-QKV)
    attn_mfma<<<Bc * NHc, 256, 0, stream>>>(qb16, kb16, vb16, code_mask, xbb);
    // x += ctx @ wo
    gemm_mfma<false, false, true, false><<<dim3(2, 256), 256, 0, stream>>>(
        xbb, woT, nullptr, xbuf, xbuf, 256, 256);
    // xb = bf16(x) for FFN
    convert_bf16<<<4096, 256, 0, stream>>>(xbuf, xbb);
    // FFN in 2 row-chunks of 16384; hidden bf16 in dead k-buffer
    for (int ch = 0; ch < 2; ++ch) {
      const unsigned short* xc = xbb + (size_t)ch * 16384 * 256;
      float* rc = xbuf + (size_t)ch * 16384 * 256;
      float* oc = final_out + (size_t)ch * 16384 * 256;
      gemm_mfma<true, true, false, true><<<dim3(8, 128), 256, 0, stream>>>(
          xc, fw1T, fb1, nullptr, hid, 1024, 256);
      gemm_mfma<true, false, true, false><<<dim3(2, 128), 256, 0, stream>>>(
          hid, fw2T, fb2, rc, oc, 256, 1024);
    }
  };

  // 2) visit stream
  gather_rows_f4<<<8192, 256, 0, stream>>>(input_ids,
                                           (const float4*)embed_inputs_w,
                                           (float4*)xbuf);
  run_encoder((const float*)d_in[13], (const float*)d_in[14],
              (const float*)d_in[15], (const float*)d_in[16],
              (const float*)d_in[17], (const float*)d_in[18],
              (const float*)d_in[19], (const float*)d_in[20], out);

  // 3) dag stream
  gather_rows_f4<<<8192, 256, 0, stream>>>(input_ids, (const float4*)dict,
                                           (float4*)xbuf);
  run_encoder((const float*)d_in[21], (const float*)d_in[22],
              (const float*)d_in[23], (const float*)d_in[24],
              (const float*)d_in[25], (const float*)d_in[26],
              (const float*)d_in[27], (const float*)d_in[28], xbuf);

  pool_kernel<<<Bc, 256, 0, stream>>>(xbuf, code_mask, pool_w, pool_b,
                                      out + 8388608);
}

// Round 5
// 760.275 us; speedup vs baseline: 4.4058x; 1.1263x over previous
//
#include <hip/hip_runtime.h>
#include <hip/hip_bf16.h>
#include <math.h>

#define VERY_NEG (-1e30f)

// B=128, S=256, H=256, C=20000, NODES=25000, A=8, NH=8, d=32, FF=1024
constexpr int Bc = 128, Sc = 256, Hc = 256, Cc = 20000, Ac = 8, NHc = 8, DHc = 32, FFc = 1024;
constexpr int Mc = Bc * Sc;  // 32768 rows
constexpr int Rc = Cc * Ac;  // 160000 dag rows

typedef __attribute__((ext_vector_type(8))) short short8;
typedef __attribute__((ext_vector_type(4))) float floatx4;

static __device__ __forceinline__ unsigned short f2bf(float f) {
  union { float f; unsigned u; } v; v.f = f;
  unsigned r = v.u + 0x7FFF + ((v.u >> 16) & 1);   // RNE
  return (unsigned short)(r >> 16);
}
static __device__ __forceinline__ unsigned pack2(float lo, float hi) {
  return (unsigned)f2bf(lo) | ((unsigned)f2bf(hi) << 16);
}

// async global->LDS, 16B per lane. LDS dest must be wave-uniform base;
// lane i lands at base + i*16 (m97-verified width-16 path).
static __device__ __forceinline__ void glds16(const unsigned short* g,
                                              unsigned short* l) {
  __builtin_amdgcn_global_load_lds(
      (const __attribute__((address_space(1))) void*)g,
      (__attribute__((address_space(3))) void*)l, 16, 0, 0);
}

// ---------------------------------------------------------------------------
// Weight prep: W[K,N] fp32 -> Wt[N,K] bf16.  Klog2 = log2(K).
// ---------------------------------------------------------------------------
__global__ __launch_bounds__(256) void transpose_bf16(
    const float* __restrict__ w, unsigned short* __restrict__ wT, int Klog2,
    int N) {
  int gid = blockIdx.x * 256 + threadIdx.x;
  int K = 1 << Klog2;
  int k = gid & (K - 1);
  int n = gid >> Klog2;
  wT[gid] = f2bf(w[(size_t)k * N + n]);
}

// ---------------------------------------------------------------------------
// bf16 MFMA GEMM with global_load_lds staging.
// C[M,N] = A[M,K] @ Bt[N,K]^T. 128x128 tile, 4 waves (2x2 of 64x64),
// 16x16x32 MFMA, BK=32. LDS tiles UNPADDED [128][32] (glds requirement).
// OUT: 0 = fp32->Cf; 1 = bf16->C2; 2 = fp32->Cf AND bf16->C2;
//      3 = bf16 QKV split (col>>8 selects buffer, 16777216-ushort stride).
// ---------------------------------------------------------------------------
template <bool BIAS, bool RELU, bool RESID, int OUT>
__global__ __launch_bounds__(256) void gemm_mfma(
    const unsigned short* __restrict__ A, const unsigned short* __restrict__ Bt,
    const float* __restrict__ bias, const float* __restrict__ resid,
    float* __restrict__ Cf, unsigned short* __restrict__ C2, int N, int K) {
  __shared__ unsigned short As[128 * 32];
  __shared__ unsigned short Bs[128 * 32];
  const int tid = threadIdx.x;
  const int rowBase = blockIdx.y * 128;
  const int colBase = blockIdx.x * 128;
  const int wave = tid >> 6, lane = tid & 63;
  const int wm = wave >> 1, wn = wave & 1;
  const int quad = lane >> 4, l15 = lane & 15;
  // staging: granule = 8 ushorts (16B); g = row*4 + kseg; 8 instrs of 64
  const int srow = (wave << 5) + (lane >> 2);  // +16 per sub-instr
  const int scol = (lane & 3) << 3;

  floatx4 acc[4][4];
#pragma unroll
  for (int mt = 0; mt < 4; ++mt)
#pragma unroll
    for (int nt = 0; nt < 4; ++nt) acc[mt][nt] = (floatx4){0.f, 0.f, 0.f, 0.f};

  for (int k0 = 0; k0 < K; k0 += 32) {
#pragma unroll
    for (int i = 0; i < 2; ++i) {
      int row = srow + (i << 4);
      int lb = (((wave << 1) + i) << 9);  // granule-base*8 ushorts
      glds16(A + (size_t)(rowBase + row) * K + k0 + scol, &As[lb]);
      glds16(Bt + (size_t)(colBase + row) * K + k0 + scol, &Bs[lb]);
    }
    __syncthreads();  // drains vmcnt(0) then s_barrier (m97 structure)
    short8 af[4], bfr[4];
#pragma unroll
    for (int mt = 0; mt < 4; ++mt)
      af[mt] = *(const short8*)&As[(wm * 64 + mt * 16 + l15) * 32 + quad * 8];
#pragma unroll
    for (int nt = 0; nt < 4; ++nt)
      bfr[nt] = *(const short8*)&Bs[(wn * 64 + nt * 16 + l15) * 32 + quad * 8];
#pragma unroll
    for (int mt = 0; mt < 4; ++mt)
#pragma unroll
      for (int nt = 0; nt < 4; ++nt)
        acc[mt][nt] = __builtin_amdgcn_mfma_f32_16x16x32_bf16(
            af[mt], bfr[nt], acc[mt][nt], 0, 0, 0);
    __syncthreads();
  }

#pragma unroll
  for (int mt = 0; mt < 4; ++mt) {
#pragma unroll
    for (int nt = 0; nt < 4; ++nt) {
      int col = colBase + wn * 64 + nt * 16 + l15;
      float bz = BIAS ? bias[col] : 0.f;
#pragma unroll
      for (int i = 0; i < 4; ++i) {
        int row = rowBase + wm * 64 + mt * 16 + quad * 4 + i;
        float v = acc[mt][nt][i];
        if (BIAS) v += bz;
        if (RELU) v = fmaxf(v, 0.f);
        if (RESID) v += resid[(size_t)row * N + col];
        if (OUT == 0) {
          Cf[(size_t)row * N + col] = v;
        } else if (OUT == 1) {
          C2[(size_t)row * N + col] = f2bf(v);
        } else if (OUT == 2) {
          Cf[(size_t)row * N + col] = v;
          C2[(size_t)row * N + col] = f2bf(v);
        } else {  // QKV split
          C2[(size_t)(col >> 8) * 16777216 + (size_t)row * 256 + (col & 255)] =
              f2bf(v);
        }
      }
    }
  }
}

// ---------------------------------------------------------------------------
// DAG stage 0: w1 [512,256] fp32 -> w1T [256,512] bf16
// ---------------------------------------------------------------------------
__global__ __launch_bounds__(256) void prep_w1T(const float* __restrict__ w1,
                                                unsigned short* __restrict__ w1T) {
  int gid = blockIdx.x * 256 + threadIdx.x;
  int n = gid >> 9, k = gid & 511;
  w1T[(size_t)n * 512 + k] = f2bf(w1[(size_t)k * 256 + n]);
}

// ---------------------------------------------------------------------------
// DAG stage 1: A [160000, 512] bf16 = concat(leaves_emb*m, anc_emb*m)
// ---------------------------------------------------------------------------
__global__ __launch_bounds__(256) void build_A(
    const int* __restrict__ leaves, const int* __restrict__ anc,
    const float* __restrict__ masks, const float* __restrict__ emb,
    unsigned short* __restrict__ A) {
  int t = threadIdx.x;
  int row = blockIdx.x * 4 + (t >> 6);
  int lane = t & 63;
  int node = (lane < 32) ? leaves[row] : anc[row];
  float m = masks[row];
  int col = (lane & 31) * 8;
  const float* src = emb + (size_t)node * 256 + col;
  float4 a = ((const float4*)src)[0];
  float4 b = ((const float4*)src)[1];
  uint4 o;
  o.x = pack2(a.x * m, a.y * m);
  o.y = pack2(a.z * m, a.w * m);
  o.z = pack2(b.x * m, b.y * m);
  o.w = pack2(b.z * m, b.w * m);
  *(uint4*)(A + (size_t)row * 512 + lane * 8) = o;
}

// ---------------------------------------------------------------------------
// DAG stage 2: [160000,512]@[512,256] MFMA + fused relu().w2 epilogue,
// global_load_lds staging. Grid (2, 1250). s pre-zeroed.
// ---------------------------------------------------------------------------
__global__ __launch_bounds__(256) void mlp_gemm(
    const unsigned short* __restrict__ A, const unsigned short* __restrict__ Bt,
    const float* __restrict__ b1, const float* __restrict__ w2,
    float* __restrict__ s) {
  __shared__ unsigned short As[128 * 32];
  __shared__ unsigned short Bs[128 * 32];
  const int tid = threadIdx.x;
  const int rowBase = blockIdx.y * 128;
  const int colBase = blockIdx.x * 128;
  const int wave = tid >> 6, lane = tid & 63;
  const int wm = wave >> 1, wn = wave & 1;
  const int quad = lane >> 4, l15 = lane & 15;
  const int srow = (wave << 5) + (lane >> 2);
  const int scol = (lane & 3) << 3;

  floatx4 acc[4][4];
#pragma unroll
  for (int mt = 0; mt < 4; ++mt)
#pragma unroll
    for (int nt = 0; nt < 4; ++nt) acc[mt][nt] = (floatx4){0.f, 0.f, 0.f, 0.f};

  for (int k0 = 0; k0 < 512; k0 += 32) {
#pragma unroll
    for (int i = 0; i < 2; ++i) {
      int row = srow + (i << 4);
      int lb = (((wave << 1) + i) << 9);
      glds16(A + (size_t)(rowBase + row) * 512 + k0 + scol, &As[lb]);
      glds16(Bt + (size_t)(colBase + row) * 512 + k0 + scol, &Bs[lb]);
    }
    __syncthreads();
    short8 af[4], bfr[4];
#pragma unroll
    for (int mt = 0; mt < 4; ++mt)
      af[mt] = *(const short8*)&As[(wm * 64 + mt * 16 + l15) * 32 + quad * 8];
#pragma unroll
    for (int nt = 0; nt < 4; ++nt)
      bfr[nt] = *(const short8*)&Bs[(wn * 64 + nt * 16 + l15) * 32 + quad * 8];
#pragma unroll
    for (int mt = 0; mt < 4; ++mt)
#pragma unroll
      for (int nt = 0; nt < 4; ++nt)
        acc[mt][nt] = __builtin_amdgcn_mfma_f32_16x16x32_bf16(
            af[mt], bfr[nt], acc[mt][nt], 0, 0, 0);
    __syncthreads();
  }

  float b1c[4], w2c[4];
#pragma unroll
  for (int nt = 0; nt < 4; ++nt) {
    int col = colBase + wn * 64 + nt * 16 + l15;
    b1c[nt] = b1[col];
    w2c[nt] = w2[col];
  }
#pragma unroll
  for (int mt = 0; mt < 4; ++mt) {
#pragma unroll
    for (int i = 0; i < 4; ++i) {
      float p = 0.f;
#pragma unroll
      for (int nt = 0; nt < 4; ++nt) {
        float v = acc[mt][nt][i] + b1c[nt];
        p += fmaxf(v, 0.f) * w2c[nt];
      }
      p += __shfl_xor(p, 1, 64);
      p += __shfl_xor(p, 2, 64);
      p += __shfl_xor(p, 4, 64);
      p += __shfl_xor(p, 8, 64);
      if (l15 == 0)
        atomicAdd(s + rowBase + wm * 64 + mt * 16 + quad * 4 + i, p);
    }
  }
}

// ---------------------------------------------------------------------------
// DAG stage 3: softmax over A=8 + masked ancestor weighted sum -> dict.
// ---------------------------------------------------------------------------
__global__ __launch_bounds__(256) void dag_finalize(
    const float* __restrict__ s, const float* __restrict__ masks,
    const int* __restrict__ anc, const float* __restrict__ b2,
    const float* __restrict__ emb, float* __restrict__ dict) {
  const int c = blockIdx.x;
  const int t = threadIdx.x;
  __shared__ float sv[8], mv[8];
  __shared__ int nv[8];
  if (t < 8) {
    float m = masks[c * 8 + t];
    sv[t] = s[c * 8 + t] + b2[0] + (1.f - m) * VERY_NEG;
    mv[t] = m;
    nv[t] = anc[c * 8 + t];
  }
  __syncthreads();
  float mx = -INFINITY;
#pragma unroll
  for (int a = 0; a < 8; ++a) mx = fmaxf(mx, sv[a]);
  float e[8], sum = 0.f;
#pragma unroll
  for (int a = 0; a < 8; ++a) { e[a] = __expf(sv[a] - mx); sum += e[a]; }
  float inv = 1.f / sum;
  float o = 0.f;
#pragma unroll
  for (int a = 0; a < 8; ++a)
    o += e[a] * inv * mv[a] * emb[(size_t)nv[a] * 256 + t];
  dict[(size_t)(c + 1) * 256 + t] = o;
  if (c == 0) dict[t] = 0.f;
}

// ---------------------------------------------------------------------------
// Row gather -> fp32 AND bf16 (dual write; table read once).
// ---------------------------------------------------------------------------
__global__ __launch_bounds__(256) void gather_both(
    const int* __restrict__ ids, const float4* __restrict__ table,
    float4* __restrict__ outf, unsigned short* __restrict__ outb) {
  int gid = blockIdx.x * 256 + threadIdx.x;
  int row = gid >> 6;
  int c4 = gid & 63;
  float4 v = table[(size_t)ids[row] * 64 + c4];
  outf[gid] = v;
  uint2 o;
  o.x = pack2(v.x, v.y);
  o.y = pack2(v.z, v.w);
  *(uint2*)(outb + (size_t)gid * 4) = o;
}

// ---------------------------------------------------------------------------
// MFMA flash attention. One block per (b,h); 4 waves; wave owns 64 q-rows.
// ---------------------------------------------------------------------------
__global__ __launch_bounds__(256) void attn_mfma(
    const unsigned short* __restrict__ q, const unsigned short* __restrict__ k,
    const unsigned short* __restrict__ v, const float* __restrict__ cm,
    unsigned short* __restrict__ ctx) {
  __shared__ unsigned short Ks[256][40];   // [seq][d] pad->40
  __shared__ unsigned short Vt[32][264];   // [d][seq] pad->264
  __shared__ unsigned short Ps[4][64][72]; // wave-private P (also Vtmp/OsW)
  __shared__ float madd[256];
  const int b = blockIdx.x >> 3, h = blockIdx.x & 7;
  const int tid = threadIdx.x;
  const int wave = tid >> 6, lane = tid & 63;
  const int quad = lane >> 4, l15 = lane & 15;
  const size_t tokbase = (size_t)b * 256;
  const int hoff = h * 32;

  unsigned short* Vtmp = &Ps[0][0][0];  // [256][40] staging

#pragma unroll
  for (int it = 0; it < 4; ++it) {
    int idx = tid + it * 256;
    int row = idx >> 2, c = idx & 3;
    size_t g = (tokbase + row) * 256 + hoff + c * 8;
    *(uint4*)&Ks[row][c * 8] = *(const uint4*)(k + g);
    *(uint4*)(Vtmp + row * 40 + c * 8) = *(const uint4*)(v + g);
  }
  madd[tid] = (1.f - cm[b * 256 + tid]) * VERY_NEG;
  __syncthreads();
#pragma unroll
  for (int it = 0; it < 4; ++it) {
    int idx = tid + it * 256;
    int row = idx & 255, c = idx >> 8;
    uint4 w = *(const uint4*)(Vtmp + row * 40 + c * 8);
    const unsigned short* wsp = (const unsigned short*)&w;
#pragma unroll
    for (int j = 0; j < 8; ++j) Vt[c * 8 + j][row] = wsp[j];
  }
  __syncthreads();

  short8 qf[4];
#pragma unroll
  for (int mt = 0; mt < 4; ++mt) {
    size_t qrow = tokbase + wave * 64 + mt * 16 + l15;
    qf[mt] = *(const short8*)(q + qrow * 256 + hoff + quad * 8);
  }
  float madd_r[16];
#pragma unroll
  for (int nt = 0; nt < 16; ++nt) madd_r[nt] = madd[nt * 16 + l15];

  float m_r[4][4], l_r[4][4];
  floatx4 oa[4][2];
#pragma unroll
  for (int mt = 0; mt < 4; ++mt)
#pragma unroll
    for (int i = 0; i < 4; ++i) { m_r[mt][i] = -INFINITY; l_r[mt][i] = 0.f; }
#pragma unroll
  for (int mt = 0; mt < 4; ++mt)
#pragma unroll
    for (int nd = 0; nd < 2; ++nd) oa[mt][nd] = (floatx4){0.f, 0.f, 0.f, 0.f};

  const float scale = 0.17677669529663687f;  // 1/sqrt(32)

  for (int t = 0; t < 4; ++t) {
    short8 kf[4];
#pragma unroll
    for (int nt = 0; nt < 4; ++nt)
      kf[nt] = *(const short8*)&Ks[t * 64 + nt * 16 + l15][quad * 8];
    floatx4 sa[4][4];
#pragma unroll
    for (int mt = 0; mt < 4; ++mt)
#pragma unroll
      for (int nt = 0; nt < 4; ++nt) sa[mt][nt] = (floatx4){0.f, 0.f, 0.f, 0.f};
#pragma unroll
    for (int mt = 0; mt < 4; ++mt)
#pragma unroll
      for (int nt = 0; nt < 4; ++nt)
        sa[mt][nt] = __builtin_amdgcn_mfma_f32_16x16x32_bf16(
            qf[mt], kf[nt], sa[mt][nt], 0, 0, 0);

#pragma unroll
    for (int mt = 0; mt < 4; ++mt) {
#pragma unroll
      for (int i = 0; i < 4; ++i) {
        float rmax = -INFINITY;
#pragma unroll
        for (int nt = 0; nt < 4; ++nt) {
          float sv = sa[mt][nt][i] * scale + madd_r[t * 4 + nt];
          sa[mt][nt][i] = sv;
          rmax = fmaxf(rmax, sv);
        }
        rmax = fmaxf(rmax, __shfl_xor(rmax, 1, 64));
        rmax = fmaxf(rmax, __shfl_xor(rmax, 2, 64));
        rmax = fmaxf(rmax, __shfl_xor(rmax, 4, 64));
        rmax = fmaxf(rmax, __shfl_xor(rmax, 8, 64));
        float mn = fmaxf(m_r[mt][i], rmax);
        float alpha = __expf(m_r[mt][i] - mn);
        m_r[mt][i] = mn;
        float rs = 0.f;
#pragma unroll
        for (int nt = 0; nt < 4; ++nt) {
          float p = __expf(sa[mt][nt][i] - mn);
          sa[mt][nt][i] = p;
          rs += p;
        }
        rs += __shfl_xor(rs, 1, 64);
        rs += __shfl_xor(rs, 2, 64);
        rs += __shfl_xor(rs, 4, 64);
        rs += __shfl_xor(rs, 8, 64);
        l_r[mt][i] = l_r[mt][i] * alpha + rs;
#pragma unroll
        for (int nd = 0; nd < 2; ++nd) oa[mt][nd][i] *= alpha;
      }
    }
#pragma unroll
    for (int mt = 0; mt < 4; ++mt)
#pragma unroll
      for (int nt = 0; nt < 4; ++nt)
#pragma unroll
        for (int i = 0; i < 4; ++i)
          Ps[wave][mt * 16 + quad * 4 + i][nt * 16 + l15] =
              f2bf(sa[mt][nt][i]);
    __asm__ __volatile__("s_waitcnt lgkmcnt(0)" ::: "memory");
#pragma unroll
    for (int ks = 0; ks < 2; ++ks) {
      short8 vf[2];
#pragma unroll
      for (int nd = 0; nd < 2; ++nd)
        vf[nd] =
            *(const short8*)&Vt[nd * 16 + l15][t * 64 + ks * 32 + quad * 8];
#pragma unroll
      for (int mt = 0; mt < 4; ++mt) {
        short8 pf = *(const short8*)&Ps[wave][mt * 16 + l15][ks * 32 + quad * 8];
#pragma unroll
        for (int nd = 0; nd < 2; ++nd)
          oa[mt][nd] = __builtin_amdgcn_mfma_f32_16x16x32_bf16(
              pf, vf[nd], oa[mt][nd], 0, 0, 0);
      }
    }
    __asm__ __volatile__("s_waitcnt lgkmcnt(0)" ::: "memory");
  }

  unsigned short* OsW = &Ps[wave][0][0];
#pragma unroll
  for (int mt = 0; mt < 4; ++mt)
#pragma unroll
    for (int nd = 0; nd < 2; ++nd)
#pragma unroll
      for (int i = 0; i < 4; ++i)
        OsW[(mt * 16 + quad * 4 + i) * 40 + nd * 16 + l15] =
            f2bf(oa[mt][nd][i] / l_r[mt][i]);
  __asm__ __volatile__("s_waitcnt lgkmcnt(0)" ::: "memory");
#pragma unroll
  for (int it = 0; it < 4; ++it) {
    int idx = it * 64 + lane;
    int row = idx >> 2, c = idx & 3;
    uint4 w = *(const uint4*)(OsW + row * 40 + c * 8);
    *(uint4*)(ctx + (tokbase + wave * 64 + row) * 256 + hoff + c * 8) = w;
  }
}

// ---------------------------------------------------------------------------
// Attention pooling. 128 blocks (one per batch), 256 thr.
// ---------------------------------------------------------------------------
__global__ __launch_bounds__(256) void pool_kernel(
    const float* __restrict__ x, const float* __restrict__ code_mask,
    const float* __restrict__ pw, const float* __restrict__ pb,
    float* __restrict__ out) {
  const int b = blockIdx.x;
  const int t = threadIdx.x;
  __shared__ float ss[256];
  __shared__ float red[256];
  __shared__ float als[256];
  const float* xb = x + (size_t)b * 256 * 256;

  float s = pb[0];
  for (int j = 0; j < 256; j += 4) {
    float4 xv = *(const float4*)(xb + (size_t)t * 256 + j);
    float4 wv = *(const float4*)(pw + j);
    s += xv.x * wv.x + xv.y * wv.y + xv.z * wv.z + xv.w * wv.w;
  }
  s += (1.f - code_mask[b * 256 + t]) * VERY_NEG;
  ss[t] = s; red[t] = s;
  __syncthreads();
  for (int off = 128; off > 0; off >>= 1) {
    if (t < off) red[t] = fmaxf(red[t], red[t + off]);
    __syncthreads();
  }
  float m = red[0];
  __syncthreads();
  float e = __expf(ss[t] - m);
  als[t] = e; red[t] = e;
  __syncthreads();
  for (int off = 128; off > 0; off >>= 1) {
    if (t < off) red[t] += red[t + off];
    __syncthreads();
  }
  float inv = 1.f / red[0];
  float o = 0.f;
  for (int si = 0; si < 256; ++si) o += als[si] * xb[(size_t)si * 256 + t];
  out[b * 256 + t] = o * inv;
}

// ---------------------------------------------------------------------------
extern "C" void kernel_launch(void* const* d_in, const int* in_sizes, int n_in,
                              void* d_out, int out_size, void* d_ws,
                              size_t ws_size, hipStream_t stream) {
  const int* input_ids = (const int*)d_in[0];
  const float* code_mask = (const float*)d_in[1];
  const int* dx_leaves = (const int*)d_in[2];
  const int* dx_anc = (const int*)d_in[3];
  const float* dx_masks = (const float*)d_in[4];
  const float* embed_init_w = (const float*)d_in[5];
  const float* embed_inputs_w = (const float*)d_in[6];
  const float* attn_w1 = (const float*)d_in[7];
  const float* attn_b1 = (const float*)d_in[8];
  const float* attn_w2 = (const float*)d_in[9];
  const float* attn_b2 = (const float*)d_in[10];
  const float* pool_w = (const float*)d_in[11];
  const float* pool_b = (const float*)d_in[12];

  float* out = (float*)d_out;
  float* ws = (float*)d_ws;

  // workspace layout (floats)
  float* dict = ws;                      // 5,120,256
  float* xbuf = dict + 5120256;          // 8,388,608
  float* qb   = xbuf + 8388608;          // 8,388,608
  float* kb   = qb + 8388608;            // 8,388,608
  float* vb   = kb + 8388608;            // 8,388,608
  float* ctxb = vb + 8388608;            // 8,388,608
  float* wend = ctxb + 8388608;          // weight area

  // DAG-phase aliases over the (currently dead) xbuf..ctxb region:
  unsigned short* Abf = (unsigned short*)xbuf;
  float* sbuf = xbuf + 40960000;
  unsigned short* w1T_dag = (unsigned short*)(xbuf + 41120000);

  // encoder-phase aliases:
  unsigned short* xb16  = (unsigned short*)ctxb;  // bf16(x) pre-QKV, later ctx
  unsigned short* qkv16 = (unsigned short*)qb;    // q/k/v bf16, 16777216 stride
  unsigned short* xq16  = (unsigned short*)qb;    // bf16(x) post-WO (q dead)
  unsigned short* hid16 = (unsigned short*)kb;    // FFN hidden [32768][1024] (k+v)
  // bf16 weights (wq/wk/wv contiguous -> fused QKV Bt of 768 rows):
  unsigned short* wqT  = (unsigned short*)wend;
  unsigned short* wkT  = wqT + 65536;
  unsigned short* wvT  = wkT + 65536;
  unsigned short* woT  = wvT + 65536;
  unsigned short* fw1T = woT + 65536;
  unsigned short* fw2T = fw1T + 262144;

  // 1) DAG embedding -> dict_matrix (bf16 MFMA pipeline)
  hipMemsetAsync(sbuf, 0, Rc * sizeof(float), stream);
  prep_w1T<<<512, 256, 0, stream>>>(attn_w1, w1T_dag);
  build_A<<<Rc / 4, 256, 0, stream>>>(dx_leaves, dx_anc, dx_masks,
                                      embed_init_w, Abf);
  mlp_gemm<<<dim3(2, Rc / 128), 256, 0, stream>>>(Abf, w1T_dag, attn_b1,
                                                  attn_w2, sbuf);
  dag_finalize<<<Cc, 256, 0, stream>>>(sbuf, dx_masks, dx_anc, attn_b2,
                                       embed_init_w, dict);

  auto run_encoder = [&](const float* wq, const float* wk, const float* wv,
                         const float* wo, const float* fw1, const float* fb1,
                         const float* fw2, const float* fb2, float* final_out) {
    transpose_bf16<<<256, 256, 0, stream>>>(wq, wqT, 8, 256);
    transpose_bf16<<<256, 256, 0, stream>>>(wk, wkT, 8, 256);
    transpose_bf16<<<256, 256, 0, stream>>>(wv, wvT, 8, 256);
    transpose_bf16<<<256, 256, 0, stream>>>(wo, woT, 8, 256);
    transpose_bf16<<<1024, 256, 0, stream>>>(fw1, fw1T, 8, 1024);
    transpose_bf16<<<1024, 256, 0, stream>>>(fw2, fw2T, 10, 256);

    // fused QKV: N=768, bf16 split-output into q/k/v buffers
    gemm_mfma<false, false, false, 3><<<dim3(6, 256), 256, 0, stream>>>(
        xb16, wqT, nullptr, nullptr, nullptr, qkv16, 256, 256);
    // MFMA flash attention -> bf16 ctx (into xb16 region; dead post-QKV)
    attn_mfma<<<Bc * NHc, 256, 0, stream>>>(qkv16, qkv16 + 16777216,
                                            qkv16 + 33554432, code_mask, xb16);
    // x += ctx @ wo  (fp32 resid out to xbuf, bf16 copy to xq16)
    gemm_mfma<false, false, true, 2><<<dim3(2, 256), 256, 0, stream>>>(
        xb16, woT, nullptr, xbuf, xbuf, xq16, 256, 256);
    // FFN (full M): hidden bf16 in dead k+v buffers
    gemm_mfma<true, true, false, 1><<<dim3(8, 256), 256, 0, stream>>>(
        xq16, fw1T, fb1, nullptr, nullptr, hid16, 1024, 256);
    gemm_mfma<true, false, true, 0><<<dim3(2, 256), 256, 0, stream>>>(
        hid16, fw2T, fb2, xbuf, final_out, nullptr, 256, 1024);
  };

  // 2) visit stream
  gather_both<<<8192, 256, 0, stream>>>(input_ids,
                                        (const float4*)embed_inputs_w,
                                        (float4*)xbuf, xb16);
  run_encoder((const float*)d_in[13], (const float*)d_in[14],
              (const float*)d_in[15], (const float*)d_in[16],
              (const float*)d_in[17], (const float*)d_in[18],
              (const float*)d_in[19], (const float*)d_in[20], out);

  // 3) dag stream
  gather_both<<<8192, 256, 0, stream>>>(input_ids, (const float4*)dict,
                                        (float4*)xbuf, xb16);
  run_encoder((const float*)d_in[21], (const float*)d_in[22],
              (const float*)d_in[23], (const float*)d_in[24],
              (const float*)d_in[25], (const float*)d_in[26],
              (const float*)d_in[27], (const float*)d_in[28], xbuf);

  pool_kernel<<<Bc, 256, 0, stream>>>(xbuf, code_mask, pool_w, pool_b,
                                      out + 8388608);
}

// Round 6
// 730.607 us; speedup vs baseline: 4.5847x; 1.0406x over previous
//
#include <hip/hip_runtime.h>
#include <hip/hip_bf16.h>
#include <math.h>

#define VERY_NEG (-1e30f)

// B=128, S=256, H=256, C=20000, NODES=25000, A=8, NH=8, d=32, FF=1024
constexpr int Bc = 128, Sc = 256, Hc = 256, Cc = 20000, Ac = 8, NHc = 8, DHc = 32, FFc = 1024;
constexpr int Mc = Bc * Sc;  // 32768 rows
constexpr int Rc = Cc * Ac;  // 160000 dag rows

typedef __attribute__((ext_vector_type(8))) short short8;
typedef __attribute__((ext_vector_type(4))) float floatx4;

static __device__ __forceinline__ unsigned short f2bf(float f) {
  union { float f; unsigned u; } v; v.f = f;
  unsigned r = v.u + 0x7FFF + ((v.u >> 16) & 1);   // RNE
  return (unsigned short)(r >> 16);
}
static __device__ __forceinline__ unsigned pack2(float lo, float hi) {
  return (unsigned)f2bf(lo) | ((unsigned)f2bf(hi) << 16);
}

// async global->LDS, 16B per lane; lane i lands at base + i*16.
static __device__ __forceinline__ void glds16(const unsigned short* g,
                                              unsigned short* l) {
  __builtin_amdgcn_global_load_lds(
      (const __attribute__((address_space(1))) void*)g,
      (__attribute__((address_space(3))) void*)l, 16, 0, 0);
}

// ---------------------------------------------------------------------------
// Per-layer weight prep, one launch: wq/wk/wv -> qkvT[768][256],
// wo -> woT[256][256], fw1 -> fw1T[1024][256], fw2 -> fw2T[256][1024].
// 3072 blocks x 256.
// ---------------------------------------------------------------------------
__global__ __launch_bounds__(256) void prep_weights(
    const float* __restrict__ wq, const float* __restrict__ wk,
    const float* __restrict__ wv, const float* __restrict__ wo,
    const float* __restrict__ fw1, const float* __restrict__ fw2,
    unsigned short* __restrict__ qkvT, unsigned short* __restrict__ woT,
    unsigned short* __restrict__ fw1T, unsigned short* __restrict__ fw2T) {
  int gid = blockIdx.x * 256 + threadIdx.x;
  if (gid < 196608) {
    int which = gid >> 16, rem = gid & 65535;
    int n = rem >> 8, k = rem & 255;
    const float* w = which == 0 ? wq : (which == 1 ? wk : wv);
    qkvT[gid] = f2bf(w[k * 256 + n]);
  } else if (gid < 262144) {
    int rem = gid - 196608;
    int n = rem >> 8, k = rem & 255;
    woT[rem] = f2bf(wo[k * 256 + n]);
  } else if (gid < 524288) {
    int rem = gid - 262144;
    int n = rem >> 8, k = rem & 255;   // n 0..1023
    fw1T[rem] = f2bf(fw1[k * 1024 + n]);
  } else {
    int rem = gid - 524288;
    int n = rem >> 10, k = rem & 1023; // n 0..255
    fw2T[rem] = f2bf(fw2[k * 256 + n]);
  }
}

// ---------------------------------------------------------------------------
// bf16 MFMA GEMM, glds staging, BK=64, XOR-swizzled unpadded LDS [128][64].
// Storage: granule (row, p) holds global chunk p^(row&7); staging lane loads
// chunk (lane&7)^(lane>>3); fragment reads position ((kk*4+quad)^(l15&7)).
// OUT: 0 fp32->Cf; 1 bf16->C2; 2 both; 3 bf16 QKV split (col>>8 buffer).
// ---------------------------------------------------------------------------
template <int K, bool BIAS, bool RELU, bool RESID, int OUT>
__global__ __launch_bounds__(256) void gemm_mfma(
    const unsigned short* __restrict__ A, const unsigned short* __restrict__ Bt,
    const float* __restrict__ bias, const float* __restrict__ resid,
    float* __restrict__ Cf, unsigned short* __restrict__ C2, int N) {
  __shared__ unsigned short As[128 * 64];
  __shared__ unsigned short Bs[128 * 64];
  const int tid = threadIdx.x;
  const int rowBase = blockIdx.y * 128;
  const int colBase = blockIdx.x * 128;
  const int wave = tid >> 6, lane = tid & 63;
  const int wm = wave >> 1, wn = wave & 1;
  const int quad = lane >> 4, l15 = lane & 15;
  const int s8 = (((lane & 7) ^ (lane >> 3)) << 3);  // swizzled global chunk
  const int rs0 = (wave << 5) + (lane >> 3);         // staged row base
  const int swz = l15 & 7;

  floatx4 acc[4][4];
#pragma unroll
  for (int mt = 0; mt < 4; ++mt)
#pragma unroll
    for (int nt = 0; nt < 4; ++nt) acc[mt][nt] = (floatx4){0.f, 0.f, 0.f, 0.f};

  for (int k0 = 0; k0 < K; k0 += 64) {
#pragma unroll
    for (int i = 0; i < 4; ++i) {
      int r = rs0 + (i << 3);
      int lb = wave * 2048 + i * 512;
      glds16(A + (size_t)(rowBase + r) * K + k0 + s8, &As[lb]);
      glds16(Bt + (size_t)(colBase + r) * K + k0 + s8, &Bs[lb]);
    }
    __syncthreads();
#pragma unroll
    for (int kk = 0; kk < 2; ++kk) {
      short8 af[4], bfr[4];
#pragma unroll
      for (int mt = 0; mt < 4; ++mt)
        af[mt] = *(const short8*)&As[(wm * 64 + mt * 16 + l15) * 64 +
                                     ((((kk << 2) | quad) ^ swz) << 3)];
#pragma unroll
      for (int nt = 0; nt < 4; ++nt)
        bfr[nt] = *(const short8*)&Bs[(wn * 64 + nt * 16 + l15) * 64 +
                                      ((((kk << 2) | quad) ^ swz) << 3)];
#pragma unroll
      for (int mt = 0; mt < 4; ++mt)
#pragma unroll
        for (int nt = 0; nt < 4; ++nt)
          acc[mt][nt] = __builtin_amdgcn_mfma_f32_16x16x32_bf16(
              af[mt], bfr[nt], acc[mt][nt], 0, 0, 0);
    }
    __syncthreads();
  }

#pragma unroll
  for (int mt = 0; mt < 4; ++mt) {
#pragma unroll
    for (int nt = 0; nt < 4; ++nt) {
      int col = colBase + wn * 64 + nt * 16 + l15;
      float bz = BIAS ? bias[col] : 0.f;
#pragma unroll
      for (int i = 0; i < 4; ++i) {
        int row = rowBase + wm * 64 + mt * 16 + quad * 4 + i;
        float v = acc[mt][nt][i];
        if (BIAS) v += bz;
        if (RELU) v = fmaxf(v, 0.f);
        if (RESID) v += resid[(size_t)row * N + col];
        if (OUT == 0) {
          Cf[(size_t)row * N + col] = v;
        } else if (OUT == 1) {
          C2[(size_t)row * N + col] = f2bf(v);
        } else if (OUT == 2) {
          Cf[(size_t)row * N + col] = v;
          C2[(size_t)row * N + col] = f2bf(v);
        } else {  // QKV split
          C2[(size_t)(col >> 8) * 16777216 + (size_t)row * 256 + (col & 255)] =
              f2bf(v);
        }
      }
    }
  }
}

// ---------------------------------------------------------------------------
// DAG stage 0: w1 [512,256] fp32 -> w1T [256,512] bf16
// ---------------------------------------------------------------------------
__global__ __launch_bounds__(256) void prep_w1T(const float* __restrict__ w1,
                                                unsigned short* __restrict__ w1T) {
  int gid = blockIdx.x * 256 + threadIdx.x;
  int n = gid >> 9, k = gid & 511;
  w1T[(size_t)n * 512 + k] = f2bf(w1[(size_t)k * 256 + n]);
}

// ---------------------------------------------------------------------------
// DAG stage 1: A [160000, 512] bf16 = concat(leaves_emb*m, anc_emb*m)
// ---------------------------------------------------------------------------
__global__ __launch_bounds__(256) void build_A(
    const int* __restrict__ leaves, const int* __restrict__ anc,
    const float* __restrict__ masks, const float* __restrict__ emb,
    unsigned short* __restrict__ A) {
  int t = threadIdx.x;
  int row = blockIdx.x * 4 + (t >> 6);
  int lane = t & 63;
  int node = (lane < 32) ? leaves[row] : anc[row];
  float m = masks[row];
  int col = (lane & 31) * 8;
  const float* src = emb + (size_t)node * 256 + col;
  float4 a = ((const float4*)src)[0];
  float4 b = ((const float4*)src)[1];
  uint4 o;
  o.x = pack2(a.x * m, a.y * m);
  o.y = pack2(a.z * m, a.w * m);
  o.z = pack2(b.x * m, b.y * m);
  o.w = pack2(b.z * m, b.w * m);
  *(uint4*)(A + (size_t)row * 512 + lane * 8) = o;
}

// ---------------------------------------------------------------------------
// DAG stage 2: [160000,512]@[512,256] MFMA + fused relu().w2 epilogue.
// BK=64 swizzled glds staging (same scheme as gemm_mfma). Grid (2, 1250).
// ---------------------------------------------------------------------------
__global__ __launch_bounds__(256) void mlp_gemm(
    const unsigned short* __restrict__ A, const unsigned short* __restrict__ Bt,
    const float* __restrict__ b1, const float* __restrict__ w2,
    float* __restrict__ s) {
  __shared__ unsigned short As[128 * 64];
  __shared__ unsigned short Bs[128 * 64];
  const int tid = threadIdx.x;
  const int rowBase = blockIdx.y * 128;
  const int colBase = blockIdx.x * 128;
  const int wave = tid >> 6, lane = tid & 63;
  const int wm = wave >> 1, wn = wave & 1;
  const int quad = lane >> 4, l15 = lane & 15;
  const int s8 = (((lane & 7) ^ (lane >> 3)) << 3);
  const int rs0 = (wave << 5) + (lane >> 3);
  const int swz = l15 & 7;

  floatx4 acc[4][4];
#pragma unroll
  for (int mt = 0; mt < 4; ++mt)
#pragma unroll
    for (int nt = 0; nt < 4; ++nt) acc[mt][nt] = (floatx4){0.f, 0.f, 0.f, 0.f};

  for (int k0 = 0; k0 < 512; k0 += 64) {
#pragma unroll
    for (int i = 0; i < 4; ++i) {
      int r = rs0 + (i << 3);
      int lb = wave * 2048 + i * 512;
      glds16(A + (size_t)(rowBase + r) * 512 + k0 + s8, &As[lb]);
      glds16(Bt + (size_t)(colBase + r) * 512 + k0 + s8, &Bs[lb]);
    }
    __syncthreads();
#pragma unroll
    for (int kk = 0; kk < 2; ++kk) {
      short8 af[4], bfr[4];
#pragma unroll
      for (int mt = 0; mt < 4; ++mt)
        af[mt] = *(const short8*)&As[(wm * 64 + mt * 16 + l15) * 64 +
                                     ((((kk << 2) | quad) ^ swz) << 3)];
#pragma unroll
      for (int nt = 0; nt < 4; ++nt)
        bfr[nt] = *(const short8*)&Bs[(wn * 64 + nt * 16 + l15) * 64 +
                                      ((((kk << 2) | quad) ^ swz) << 3)];
#pragma unroll
      for (int mt = 0; mt < 4; ++mt)
#pragma unroll
        for (int nt = 0; nt < 4; ++nt)
          acc[mt][nt] = __builtin_amdgcn_mfma_f32_16x16x32_bf16(
              af[mt], bfr[nt], acc[mt][nt], 0, 0, 0);
    }
    __syncthreads();
  }

  float b1c[4], w2c[4];
#pragma unroll
  for (int nt = 0; nt < 4; ++nt) {
    int col = colBase + wn * 64 + nt * 16 + l15;
    b1c[nt] = b1[col];
    w2c[nt] = w2[col];
  }
#pragma unroll
  for (int mt = 0; mt < 4; ++mt) {
#pragma unroll
    for (int i = 0; i < 4; ++i) {
      float p = 0.f;
#pragma unroll
      for (int nt = 0; nt < 4; ++nt) {
        float v = acc[mt][nt][i] + b1c[nt];
        p += fmaxf(v, 0.f) * w2c[nt];
      }
      p += __shfl_xor(p, 1, 64);
      p += __shfl_xor(p, 2, 64);
      p += __shfl_xor(p, 4, 64);
      p += __shfl_xor(p, 8, 64);
      if (l15 == 0)
        atomicAdd(s + rowBase + wm * 64 + mt * 16 + quad * 4 + i, p);
    }
  }
}

// ---------------------------------------------------------------------------
// DAG stage 3: softmax over A=8 + masked ancestor weighted sum -> dict.
// ---------------------------------------------------------------------------
__global__ __launch_bounds__(256) void dag_finalize(
    const float* __restrict__ s, const float* __restrict__ masks,
    const int* __restrict__ anc, const float* __restrict__ b2,
    const float* __restrict__ emb, float* __restrict__ dict) {
  const int c = blockIdx.x;
  const int t = threadIdx.x;
  __shared__ float sv[8], mv[8];
  __shared__ int nv[8];
  if (t < 8) {
    float m = masks[c * 8 + t];
    sv[t] = s[c * 8 + t] + b2[0] + (1.f - m) * VERY_NEG;
    mv[t] = m;
    nv[t] = anc[c * 8 + t];
  }
  __syncthreads();
  float mx = -INFINITY;
#pragma unroll
  for (int a = 0; a < 8; ++a) mx = fmaxf(mx, sv[a]);
  float e[8], sum = 0.f;
#pragma unroll
  for (int a = 0; a < 8; ++a) { e[a] = __expf(sv[a] - mx); sum += e[a]; }
  float inv = 1.f / sum;
  float o = 0.f;
#pragma unroll
  for (int a = 0; a < 8; ++a)
    o += e[a] * inv * mv[a] * emb[(size_t)nv[a] * 256 + t];
  dict[(size_t)(c + 1) * 256 + t] = o;
  if (c == 0) dict[t] = 0.f;
}

// ---------------------------------------------------------------------------
// Row gather -> fp32 AND bf16 (dual write; table read once).
// ---------------------------------------------------------------------------
__global__ __launch_bounds__(256) void gather_both(
    const int* __restrict__ ids, const float4* __restrict__ table,
    float4* __restrict__ outf, unsigned short* __restrict__ outb) {
  int gid = blockIdx.x * 256 + threadIdx.x;
  int row = gid >> 6;
  int c4 = gid & 63;
  float4 v = table[(size_t)ids[row] * 64 + c4];
  outf[gid] = v;
  uint2 o;
  o.x = pack2(v.x, v.y);
  o.y = pack2(v.z, v.w);
  *(uint2*)(outb + (size_t)gid * 4) = o;
}

// ---------------------------------------------------------------------------
// MFMA flash attention. One block per (b,h); 4 waves; wave owns 64 q-rows.
// ---------------------------------------------------------------------------
__global__ __launch_bounds__(256) void attn_mfma(
    const unsigned short* __restrict__ q, const unsigned short* __restrict__ k,
    const unsigned short* __restrict__ v, const float* __restrict__ cm,
    unsigned short* __restrict__ ctx) {
  __shared__ unsigned short Ks[256][40];   // [seq][d] pad->40
  __shared__ unsigned short Vt[32][264];   // [d][seq] pad->264
  __shared__ unsigned short Ps[4][64][72]; // wave-private P (also Vtmp/OsW)
  __shared__ float madd[256];
  const int b = blockIdx.x >> 3, h = blockIdx.x & 7;
  const int tid = threadIdx.x;
  const int wave = tid >> 6, lane = tid & 63;
  const int quad = lane >> 4, l15 = lane & 15;
  const size_t tokbase = (size_t)b * 256;
  const int hoff = h * 32;

  unsigned short* Vtmp = &Ps[0][0][0];  // [256][40] staging

#pragma unroll
  for (int it = 0; it < 4; ++it) {
    int idx = tid + it * 256;
    int row = idx >> 2, c = idx & 3;
    size_t g = (tokbase + row) * 256 + hoff + c * 8;
    *(uint4*)&Ks[row][c * 8] = *(const uint4*)(k + g);
    *(uint4*)(Vtmp + row * 40 + c * 8) = *(const uint4*)(v + g);
  }
  madd[tid] = (1.f - cm[b * 256 + tid]) * VERY_NEG;
  __syncthreads();
#pragma unroll
  for (int it = 0; it < 4; ++it) {
    int idx = tid + it * 256;
    int row = idx & 255, c = idx >> 8;
    uint4 w = *(const uint4*)(Vtmp + row * 40 + c * 8);
    const unsigned short* wsp = (const unsigned short*)&w;
#pragma unroll
    for (int j = 0; j < 8; ++j) Vt[c * 8 + j][row] = wsp[j];
  }
  __syncthreads();

  short8 qf[4];
#pragma unroll
  for (int mt = 0; mt < 4; ++mt) {
    size_t qrow = tokbase + wave * 64 + mt * 16 + l15;
    qf[mt] = *(const short8*)(q + qrow * 256 + hoff + quad * 8);
  }
  float madd_r[16];
#pragma unroll
  for (int nt = 0; nt < 16; ++nt) madd_r[nt] = madd[nt * 16 + l15];

  float m_r[4][4], l_r[4][4];
  floatx4 oa[4][2];
#pragma unroll
  for (int mt = 0; mt < 4; ++mt)
#pragma unroll
    for (int i = 0; i < 4; ++i) { m_r[mt][i] = -INFINITY; l_r[mt][i] = 0.f; }
#pragma unroll
  for (int mt = 0; mt < 4; ++mt)
#pragma unroll
    for (int nd = 0; nd < 2; ++nd) oa[mt][nd] = (floatx4){0.f, 0.f, 0.f, 0.f};

  const float scale = 0.17677669529663687f;  // 1/sqrt(32)

  for (int t = 0; t < 4; ++t) {
    short8 kf[4];
#pragma unroll
    for (int nt = 0; nt < 4; ++nt)
      kf[nt] = *(const short8*)&Ks[t * 64 + nt * 16 + l15][quad * 8];
    floatx4 sa[4][4];
#pragma unroll
    for (int mt = 0; mt < 4; ++mt)
#pragma unroll
      for (int nt = 0; nt < 4; ++nt) sa[mt][nt] = (floatx4){0.f, 0.f, 0.f, 0.f};
#pragma unroll
    for (int mt = 0; mt < 4; ++mt)
#pragma unroll
      for (int nt = 0; nt < 4; ++nt)
        sa[mt][nt] = __builtin_amdgcn_mfma_f32_16x16x32_bf16(
            qf[mt], kf[nt], sa[mt][nt], 0, 0, 0);

#pragma unroll
    for (int mt = 0; mt < 4; ++mt) {
#pragma unroll
      for (int i = 0; i < 4; ++i) {
        float rmax = -INFINITY;
#pragma unroll
        for (int nt = 0; nt < 4; ++nt) {
          float sv = sa[mt][nt][i] * scale + madd_r[t * 4 + nt];
          sa[mt][nt][i] = sv;
          rmax = fmaxf(rmax, sv);
        }
        rmax = fmaxf(rmax, __shfl_xor(rmax, 1, 64));
        rmax = fmaxf(rmax, __shfl_xor(rmax, 2, 64));
        rmax = fmaxf(rmax, __shfl_xor(rmax, 4, 64));
        rmax = fmaxf(rmax, __shfl_xor(rmax, 8, 64));
        float mn = fmaxf(m_r[mt][i], rmax);
        float alpha = __expf(m_r[mt][i] - mn);
        m_r[mt][i] = mn;
        float rs = 0.f;
#pragma unroll
        for (int nt = 0; nt < 4; ++nt) {
          float p = __expf(sa[mt][nt][i] - mn);
          sa[mt][nt][i] = p;
          rs += p;
        }
        rs += __shfl_xor(rs, 1, 64);
        rs += __shfl_xor(rs, 2, 64);
        rs += __shfl_xor(rs, 4, 64);
        rs += __shfl_xor(rs, 8, 64);
        l_r[mt][i] = l_r[mt][i] * alpha + rs;
#pragma unroll
        for (int nd = 0; nd < 2; ++nd) oa[mt][nd][i] *= alpha;
      }
    }
#pragma unroll
    for (int mt = 0; mt < 4; ++mt)
#pragma unroll
      for (int nt = 0; nt < 4; ++nt)
#pragma unroll
        for (int i = 0; i < 4; ++i)
          Ps[wave][mt * 16 + quad * 4 + i][nt * 16 + l15] =
              f2bf(sa[mt][nt][i]);
    __asm__ __volatile__("s_waitcnt lgkmcnt(0)" ::: "memory");
#pragma unroll
    for (int ks = 0; ks < 2; ++ks) {
      short8 vf[2];
#pragma unroll
      for (int nd = 0; nd < 2; ++nd)
        vf[nd] =
            *(const short8*)&Vt[nd * 16 + l15][t * 64 + ks * 32 + quad * 8];
#pragma unroll
      for (int mt = 0; mt < 4; ++mt) {
        short8 pf = *(const short8*)&Ps[wave][mt * 16 + l15][ks * 32 + quad * 8];
#pragma unroll
        for (int nd = 0; nd < 2; ++nd)
          oa[mt][nd] = __builtin_amdgcn_mfma_f32_16x16x32_bf16(
              pf, vf[nd], oa[mt][nd], 0, 0, 0);
      }
    }
    __asm__ __volatile__("s_waitcnt lgkmcnt(0)" ::: "memory");
  }

  unsigned short* OsW = &Ps[wave][0][0];
#pragma unroll
  for (int mt = 0; mt < 4; ++mt)
#pragma unroll
    for (int nd = 0; nd < 2; ++nd)
#pragma unroll
      for (int i = 0; i < 4; ++i)
        OsW[(mt * 16 + quad * 4 + i) * 40 + nd * 16 + l15] =
            f2bf(oa[mt][nd][i] / l_r[mt][i]);
  __asm__ __volatile__("s_waitcnt lgkmcnt(0)" ::: "memory");
#pragma unroll
  for (int it = 0; it < 4; ++it) {
    int idx = it * 64 + lane;
    int row = idx >> 2, c = idx & 3;
    uint4 w = *(const uint4*)(OsW + row * 40 + c * 8);
    *(uint4*)(ctx + (tokbase + wave * 64 + row) * 256 + hoff + c * 8) = w;
  }
}

// ---------------------------------------------------------------------------
// Attention pooling. 128 blocks (one per batch), 256 thr.
// ---------------------------------------------------------------------------
__global__ __launch_bounds__(256) void pool_kernel(
    const float* __restrict__ x, const float* __restrict__ code_mask,
    const float* __restrict__ pw, const float* __restrict__ pb,
    float* __restrict__ out) {
  const int b = blockIdx.x;
  const int t = threadIdx.x;
  __shared__ float ss[256];
  __shared__ float red[256];
  __shared__ float als[256];
  const float* xb = x + (size_t)b * 256 * 256;

  float s = pb[0];
  for (int j = 0; j < 256; j += 4) {
    float4 xv = *(const float4*)(xb + (size_t)t * 256 + j);
    float4 wv = *(const float4*)(pw + j);
    s += xv.x * wv.x + xv.y * wv.y + xv.z * wv.z + xv.w * wv.w;
  }
  s += (1.f - code_mask[b * 256 + t]) * VERY_NEG;
  ss[t] = s; red[t] = s;
  __syncthreads();
  for (int off = 128; off > 0; off >>= 1) {
    if (t < off) red[t] = fmaxf(red[t], red[t + off]);
    __syncthreads();
  }
  float m = red[0];
  __syncthreads();
  float e = __expf(ss[t] - m);
  als[t] = e; red[t] = e;
  __syncthreads();
  for (int off = 128; off > 0; off >>= 1) {
    if (t < off) red[t] += red[t + off];
    __syncthreads();
  }
  float inv = 1.f / red[0];
  float o = 0.f;
  for (int si = 0; si < 256; ++si) o += als[si] * xb[(size_t)si * 256 + t];
  out[b * 256 + t] = o * inv;
}

// ---------------------------------------------------------------------------
extern "C" void kernel_launch(void* const* d_in, const int* in_sizes, int n_in,
                              void* d_out, int out_size, void* d_ws,
                              size_t ws_size, hipStream_t stream) {
  const int* input_ids = (const int*)d_in[0];
  const float* code_mask = (const float*)d_in[1];
  const int* dx_leaves = (const int*)d_in[2];
  const int* dx_anc = (const int*)d_in[3];
  const float* dx_masks = (const float*)d_in[4];
  const float* embed_init_w = (const float*)d_in[5];
  const float* embed_inputs_w = (const float*)d_in[6];
  const float* attn_w1 = (const float*)d_in[7];
  const float* attn_b1 = (const float*)d_in[8];
  const float* attn_w2 = (const float*)d_in[9];
  const float* attn_b2 = (const float*)d_in[10];
  const float* pool_w = (const float*)d_in[11];
  const float* pool_b = (const float*)d_in[12];

  float* out = (float*)d_out;
  float* ws = (float*)d_ws;

  // workspace layout (floats)
  float* dict = ws;                      // 5,120,256
  float* xbuf = dict + 5120256;          // 8,388,608
  float* qb   = xbuf + 8388608;          // 8,388,608
  float* kb   = qb + 8388608;            // 8,388,608
  float* vb   = kb + 8388608;            // 8,388,608
  float* ctxb = vb + 8388608;            // 8,388,608
  float* wend = ctxb + 8388608;          // weight area (393,216 floats)

  // DAG-phase aliases over the (currently dead) xbuf..ctxb region:
  unsigned short* Abf = (unsigned short*)xbuf;
  float* sbuf = xbuf + 40960000;
  unsigned short* w1T_dag = (unsigned short*)(xbuf + 41120000);

  // encoder-phase aliases:
  unsigned short* xb16  = (unsigned short*)ctxb;  // bf16(x) pre-QKV, later ctx
  unsigned short* qkv16 = (unsigned short*)qb;    // q/k/v bf16, 16777216 stride
  unsigned short* xq16  = (unsigned short*)qb;    // bf16(x) post-WO (q dead)
  unsigned short* hid16 = (unsigned short*)kb;    // FFN hidden [32768][1024] (k+v)
  // bf16 weights:
  unsigned short* qkvT = (unsigned short*)wend;   // 196,608
  unsigned short* woT  = qkvT + 196608;           // 65,536
  unsigned short* fw1T = woT + 65536;             // 262,144
  unsigned short* fw2T = fw1T + 262144;           // 262,144

  // 1) DAG embedding -> dict_matrix (bf16 MFMA pipeline)
  hipMemsetAsync(sbuf, 0, Rc * sizeof(float), stream);
  prep_w1T<<<512, 256, 0, stream>>>(attn_w1, w1T_dag);
  build_A<<<Rc / 4, 256, 0, stream>>>(dx_leaves, dx_anc, dx_masks,
                                      embed_init_w, Abf);
  mlp_gemm<<<dim3(2, Rc / 128), 256, 0, stream>>>(Abf, w1T_dag, attn_b1,
                                                  attn_w2, sbuf);
  dag_finalize<<<Cc, 256, 0, stream>>>(sbuf, dx_masks, dx_anc, attn_b2,
                                       embed_init_w, dict);

  auto run_encoder = [&](const float* wq, const float* wk, const float* wv,
                         const float* wo, const float* fw1, const float* fb1,
                         const float* fw2, const float* fb2, float* final_out) {
    prep_weights<<<3072, 256, 0, stream>>>(wq, wk, wv, wo, fw1, fw2, qkvT,
                                           woT, fw1T, fw2T);
    // fused QKV: N=768, bf16 split-output into q/k/v buffers
    gemm_mfma<256, false, false, false, 3><<<dim3(6, 256), 256, 0, stream>>>(
        xb16, qkvT, nullptr, nullptr, nullptr, qkv16, 256);
    // MFMA flash attention -> bf16 ctx (into xb16 region; dead post-QKV)
    attn_mfma<<<Bc * NHc, 256, 0, stream>>>(qkv16, qkv16 + 16777216,
                                            qkv16 + 33554432, code_mask, xb16);
    // x += ctx @ wo  (fp32 resid out to xbuf, bf16 copy to xq16)
    gemm_mfma<256, false, false, true, 2><<<dim3(2, 256), 256, 0, stream>>>(
        xb16, woT, nullptr, xbuf, xbuf, xq16, 256);
    // FFN: hidden bf16 in dead k+v buffers
    gemm_mfma<256, true, true, false, 1><<<dim3(8, 256), 256, 0, stream>>>(
        xq16, fw1T, fb1, nullptr, nullptr, hid16, 1024);
    gemm_mfma<1024, true, false, true, 0><<<dim3(2, 256), 256, 0, stream>>>(
        hid16, fw2T, fb2, xbuf, final_out, nullptr, 256);
  };

  // 2) visit stream
  gather_both<<<8192, 256, 0, stream>>>(input_ids,
                                        (const float4*)embed_inputs_w,
                                        (float4*)xbuf, xb16);
  run_encoder((const float*)d_in[13], (const float*)d_in[14],
              (const float*)d_in[15], (const float*)d_in[16],
              (const float*)d_in[17], (const float*)d_in[18],
              (const float*)d_in[19], (const float*)d_in[20], out);

  // 3) dag stream
  gather_both<<<8192, 256, 0, stream>>>(input_ids, (const float4*)dict,
                                        (float4*)xbuf, xb16);
  run_encoder((const float*)d_in[21], (const float*)d_in[22],
              (const float*)d_in[23], (const float*)d_in[24],
              (const float*)d_in[25], (const float*)d_in[26],
              (const float*)d_in[27], (const float*)d_in[28], xbuf);

  pool_kernel<<<Bc, 256, 0, stream>>>(xbuf, code_mask, pool_w, pool_b,
                                      out + 8388608);
}

// Round 7
// 723.436 us; speedup vs baseline: 4.6302x; 1.0099x over previous
//
#include <hip/hip_runtime.h>
#include <hip/hip_bf16.h>
#include <math.h>

#define VERY_NEG (-1e30f)

// B=128, S=256, H=256, C=20000, NODES=25000, A=8, NH=8, d=32, FF=1024
constexpr int Bc = 128, Sc = 256, Hc = 256, Cc = 20000, Ac = 8, NHc = 8, DHc = 32, FFc = 1024;
constexpr int Mc = Bc * Sc;  // 32768 rows
constexpr int Rc = Cc * Ac;  // 160000 dag rows

typedef __attribute__((ext_vector_type(8))) short short8;
typedef __attribute__((ext_vector_type(4))) float floatx4;

static __device__ __forceinline__ unsigned short f2bf(float f) {
  union { float f; unsigned u; } v; v.f = f;
  unsigned r = v.u + 0x7FFF + ((v.u >> 16) & 1);   // RNE
  return (unsigned short)(r >> 16);
}
static __device__ __forceinline__ unsigned pack2(float lo, float hi) {
  return (unsigned)f2bf(lo) | ((unsigned)f2bf(hi) << 16);
}

// async global->LDS, 16B per lane; lane i lands at base + i*16.
static __device__ __forceinline__ void glds16(const unsigned short* g,
                                              unsigned short* l) {
  __builtin_amdgcn_global_load_lds(
      (const __attribute__((address_space(1))) void*)g,
      (__attribute__((address_space(3))) void*)l, 16, 0, 0);
}

// ---------------------------------------------------------------------------
// Per-layer weight prep, one launch: wq/wk/wv -> qkvT[768][256],
// wo -> woT[256][256], fw1 -> fw1T[1024][256], fw2 -> fw2T[256][1024].
// ---------------------------------------------------------------------------
__global__ __launch_bounds__(256) void prep_weights(
    const float* __restrict__ wq, const float* __restrict__ wk,
    const float* __restrict__ wv, const float* __restrict__ wo,
    const float* __restrict__ fw1, const float* __restrict__ fw2,
    unsigned short* __restrict__ qkvT, unsigned short* __restrict__ woT,
    unsigned short* __restrict__ fw1T, unsigned short* __restrict__ fw2T) {
  int gid = blockIdx.x * 256 + threadIdx.x;
  if (gid < 196608) {
    int which = gid >> 16, rem = gid & 65535;
    int n = rem >> 8, k = rem & 255;
    const float* w = which == 0 ? wq : (which == 1 ? wk : wv);
    qkvT[gid] = f2bf(w[k * 256 + n]);
  } else if (gid < 262144) {
    int rem = gid - 196608;
    int n = rem >> 8, k = rem & 255;
    woT[rem] = f2bf(wo[k * 256 + n]);
  } else if (gid < 524288) {
    int rem = gid - 262144;
    int n = rem >> 8, k = rem & 255;   // n 0..1023
    fw1T[rem] = f2bf(fw1[k * 1024 + n]);
  } else {
    int rem = gid - 524288;
    int n = rem >> 10, k = rem & 1023; // n 0..255
    fw2T[rem] = f2bf(fw2[k * 256 + n]);
  }
}

// ---------------------------------------------------------------------------
// bf16 MFMA GEMM, glds staging, BK=64, XOR-swizzled unpadded LDS [128][64].
// Storage: granule slot s of row r holds global chunk s^(r&7); staging lane
// loads chunk (lane&7)^(lane>>3); fragment reads slot ((kk*4+quad)^(l15&7)).
// OUT: 0 fp32->Cf; 1 bf16->C2; 2 both; 3 bf16 QKV split (col>>8 buffer).
// ---------------------------------------------------------------------------
template <int K, bool BIAS, bool RELU, bool RESID, int OUT>
__global__ __launch_bounds__(256) void gemm_mfma(
    const unsigned short* __restrict__ A, const unsigned short* __restrict__ Bt,
    const float* __restrict__ bias, const float* __restrict__ resid,
    float* __restrict__ Cf, unsigned short* __restrict__ C2, int N) {
  __shared__ unsigned short As[128 * 64];
  __shared__ unsigned short Bs[128 * 64];
  const int tid = threadIdx.x;
  const int rowBase = blockIdx.y * 128;
  const int colBase = blockIdx.x * 128;
  const int wave = tid >> 6, lane = tid & 63;
  const int wm = wave >> 1, wn = wave & 1;
  const int quad = lane >> 4, l15 = lane & 15;
  const int s8 = (((lane & 7) ^ (lane >> 3)) << 3);  // swizzled global chunk
  const int rs0 = (wave << 5) + (lane >> 3);         // staged row base
  const int swz = l15 & 7;

  floatx4 acc[4][4];
#pragma unroll
  for (int mt = 0; mt < 4; ++mt)
#pragma unroll
    for (int nt = 0; nt < 4; ++nt) acc[mt][nt] = (floatx4){0.f, 0.f, 0.f, 0.f};

  for (int k0 = 0; k0 < K; k0 += 64) {
#pragma unroll
    for (int i = 0; i < 4; ++i) {
      int r = rs0 + (i << 3);
      int lb = wave * 2048 + i * 512;
      glds16(A + (size_t)(rowBase + r) * K + k0 + s8, &As[lb]);
      glds16(Bt + (size_t)(colBase + r) * K + k0 + s8, &Bs[lb]);
    }
    __syncthreads();
#pragma unroll
    for (int kk = 0; kk < 2; ++kk) {
      short8 af[4], bfr[4];
#pragma unroll
      for (int mt = 0; mt < 4; ++mt)
        af[mt] = *(const short8*)&As[(wm * 64 + mt * 16 + l15) * 64 +
                                     ((((kk << 2) | quad) ^ swz) << 3)];
#pragma unroll
      for (int nt = 0; nt < 4; ++nt)
        bfr[nt] = *(const short8*)&Bs[(wn * 64 + nt * 16 + l15) * 64 +
                                      ((((kk << 2) | quad) ^ swz) << 3)];
#pragma unroll
      for (int mt = 0; mt < 4; ++mt)
#pragma unroll
        for (int nt = 0; nt < 4; ++nt)
          acc[mt][nt] = __builtin_amdgcn_mfma_f32_16x16x32_bf16(
              af[mt], bfr[nt], acc[mt][nt], 0, 0, 0);
    }
    __syncthreads();
  }

#pragma unroll
  for (int mt = 0; mt < 4; ++mt) {
#pragma unroll
    for (int nt = 0; nt < 4; ++nt) {
      int col = colBase + wn * 64 + nt * 16 + l15;
      float bz = BIAS ? bias[col] : 0.f;
#pragma unroll
      for (int i = 0; i < 4; ++i) {
        int row = rowBase + wm * 64 + mt * 16 + quad * 4 + i;
        float v = acc[mt][nt][i];
        if (BIAS) v += bz;
        if (RELU) v = fmaxf(v, 0.f);
        if (RESID) v += resid[(size_t)row * N + col];
        if (OUT == 0) {
          Cf[(size_t)row * N + col] = v;
        } else if (OUT == 1) {
          C2[(size_t)row * N + col] = f2bf(v);
        } else if (OUT == 2) {
          Cf[(size_t)row * N + col] = v;
          C2[(size_t)row * N + col] = f2bf(v);
        } else {  // QKV split
          C2[(size_t)(col >> 8) * 16777216 + (size_t)row * 256 + (col & 255)] =
              f2bf(v);
        }
      }
    }
  }
}

// ---------------------------------------------------------------------------
// DAG stage 0: w1 [512,256] fp32 -> w1T [256,512] bf16
// ---------------------------------------------------------------------------
__global__ __launch_bounds__(256) void prep_w1T(const float* __restrict__ w1,
                                                unsigned short* __restrict__ w1T) {
  int gid = blockIdx.x * 256 + threadIdx.x;
  int n = gid >> 9, k = gid & 511;
  w1T[(size_t)n * 512 + k] = f2bf(w1[(size_t)k * 256 + n]);
}

// ---------------------------------------------------------------------------
// DAG fused GEMM: gathers A-tiles directly from emb (leaves/anc, mask-scaled,
// bf16-packed into swizzled LDS) -- build_A eliminated. B via glds.
// [160000,512]@[512,256] + fused relu(h+b1).w2 epilogue.
// Partials stored plain (no atomics): spart[(bx*2+wn)*Rc + row].
// Grid (2, 1250).
// ---------------------------------------------------------------------------
__global__ __launch_bounds__(256) void mlp_gemm(
    const int* __restrict__ leaves, const int* __restrict__ anc,
    const float* __restrict__ masks, const float* __restrict__ emb,
    const unsigned short* __restrict__ Bt, const float* __restrict__ b1,
    const float* __restrict__ w2, float* __restrict__ spart) {
  __shared__ unsigned short As[128 * 64];
  __shared__ unsigned short Bs[128 * 64];
  const int tid = threadIdx.x;
  const int rowBase = blockIdx.y * 128;
  const int colBase = blockIdx.x * 128;
  const int wave = tid >> 6, lane = tid & 63;
  const int wm = wave >> 1, wn = wave & 1;
  const int quad = lane >> 4, l15 = lane & 15;
  const int s8 = (((lane & 7) ^ (lane >> 3)) << 3);
  const int rs0 = (wave << 5) + (lane >> 3);
  const int swz = l15 & 7;

  // gather setup: 2 threads per A row
  const int r = tid >> 1;            // 0..127
  const int c32 = (tid & 1) << 5;    // 0 or 32
  const int gr = rowBase + r;
  const int nl = leaves[gr], na = anc[gr];
  const float mval = masks[gr];
  const int rx = r & 7;
  const int gbase = c32 >> 3;        // granule chunk base (0 or 4)

  floatx4 acc[4][4];
#pragma unroll
  for (int mt = 0; mt < 4; ++mt)
#pragma unroll
    for (int nt = 0; nt < 4; ++nt) acc[mt][nt] = (floatx4){0.f, 0.f, 0.f, 0.f};

  for (int k0 = 0; k0 < 512; k0 += 64) {
    // B tile: async glds (in flight during A gather)
#pragma unroll
    for (int i = 0; i < 4; ++i) {
      int rr = rs0 + (i << 3);
      glds16(Bt + (size_t)(colBase + rr) * 512 + k0 + s8,
             &Bs[wave * 2048 + i * 512]);
    }
    // A tile: gather from emb, scale by mask, pack bf16, swizzled ds_write
    {
      const int node = (k0 < 256) ? nl : na;
      const float4* src =
          (const float4*)(emb + (size_t)node * 256 + (k0 & 255) + c32);
      float4 f[8];
#pragma unroll
      for (int j = 0; j < 8; ++j) f[j] = src[j];
#pragma unroll
      for (int j = 0; j < 4; ++j) {
        uint4 o;
        o.x = pack2(f[2 * j].x * mval, f[2 * j].y * mval);
        o.y = pack2(f[2 * j].z * mval, f[2 * j].w * mval);
        o.z = pack2(f[2 * j + 1].x * mval, f[2 * j + 1].y * mval);
        o.w = pack2(f[2 * j + 1].z * mval, f[2 * j + 1].w * mval);
        *(uint4*)&As[r * 64 + (((gbase + j) ^ rx) << 3)] = o;
      }
    }
    __syncthreads();
#pragma unroll
    for (int kk = 0; kk < 2; ++kk) {
      short8 af[4], bfr[4];
#pragma unroll
      for (int mt = 0; mt < 4; ++mt)
        af[mt] = *(const short8*)&As[(wm * 64 + mt * 16 + l15) * 64 +
                                     ((((kk << 2) | quad) ^ swz) << 3)];
#pragma unroll
      for (int nt = 0; nt < 4; ++nt)
        bfr[nt] = *(const short8*)&Bs[(wn * 64 + nt * 16 + l15) * 64 +
                                      ((((kk << 2) | quad) ^ swz) << 3)];
#pragma unroll
      for (int mt = 0; mt < 4; ++mt)
#pragma unroll
        for (int nt = 0; nt < 4; ++nt)
          acc[mt][nt] = __builtin_amdgcn_mfma_f32_16x16x32_bf16(
              af[mt], bfr[nt], acc[mt][nt], 0, 0, 0);
    }
    __syncthreads();
  }

  float b1c[4], w2c[4];
#pragma unroll
  for (int nt = 0; nt < 4; ++nt) {
    int col = colBase + wn * 64 + nt * 16 + l15;
    b1c[nt] = b1[col];
    w2c[nt] = w2[col];
  }
  float* sp = spart + (size_t)(blockIdx.x * 2 + wn) * Rc + rowBase;
#pragma unroll
  for (int mt = 0; mt < 4; ++mt) {
#pragma unroll
    for (int i = 0; i < 4; ++i) {
      float p = 0.f;
#pragma unroll
      for (int nt = 0; nt < 4; ++nt) {
        float v = acc[mt][nt][i] + b1c[nt];
        p += fmaxf(v, 0.f) * w2c[nt];
      }
      p += __shfl_xor(p, 1, 64);
      p += __shfl_xor(p, 2, 64);
      p += __shfl_xor(p, 4, 64);
      p += __shfl_xor(p, 8, 64);
      if (l15 == 0) sp[wm * 64 + mt * 16 + quad * 4 + i] = p;
    }
  }
}

// ---------------------------------------------------------------------------
// DAG stage 3: sum 4 partials, softmax over A=8, masked ancestor sum -> dict.
// ---------------------------------------------------------------------------
__global__ __launch_bounds__(256) void dag_finalize(
    const float* __restrict__ s, const float* __restrict__ masks,
    const int* __restrict__ anc, const float* __restrict__ b2,
    const float* __restrict__ emb, float* __restrict__ dict) {
  const int c = blockIdx.x;
  const int t = threadIdx.x;
  __shared__ float sv[8], mv[8];
  __shared__ int nv[8];
  if (t < 8) {
    int idx = c * 8 + t;
    float m = masks[idx];
    float ssum = s[idx] + s[Rc + idx] + s[2 * Rc + idx] + s[3 * Rc + idx];
    sv[t] = ssum + b2[0] + (1.f - m) * VERY_NEG;
    mv[t] = m;
    nv[t] = anc[idx];
  }
  __syncthreads();
  float mx = -INFINITY;
#pragma unroll
  for (int a = 0; a < 8; ++a) mx = fmaxf(mx, sv[a]);
  float e[8], sum = 0.f;
#pragma unroll
  for (int a = 0; a < 8; ++a) { e[a] = __expf(sv[a] - mx); sum += e[a]; }
  float inv = 1.f / sum;
  float o = 0.f;
#pragma unroll
  for (int a = 0; a < 8; ++a)
    o += e[a] * inv * mv[a] * emb[(size_t)nv[a] * 256 + t];
  dict[(size_t)(c + 1) * 256 + t] = o;
  if (c == 0) dict[t] = 0.f;
}

// ---------------------------------------------------------------------------
// Row gather -> fp32 AND bf16 (dual write; table read once).
// ---------------------------------------------------------------------------
__global__ __launch_bounds__(256) void gather_both(
    const int* __restrict__ ids, const float4* __restrict__ table,
    float4* __restrict__ outf, unsigned short* __restrict__ outb) {
  int gid = blockIdx.x * 256 + threadIdx.x;
  int row = gid >> 6;
  int c4 = gid & 63;
  float4 v = table[(size_t)ids[row] * 64 + c4];
  outf[gid] = v;
  uint2 o;
  o.x = pack2(v.x, v.y);
  o.y = pack2(v.z, v.w);
  *(uint2*)(outb + (size_t)gid * 4) = o;
}

// ---------------------------------------------------------------------------
// MFMA flash attention. One block per (b,h); 4 waves; wave owns 64 q-rows.
// ---------------------------------------------------------------------------
__global__ __launch_bounds__(256) void attn_mfma(
    const unsigned short* __restrict__ q, const unsigned short* __restrict__ k,
    const unsigned short* __restrict__ v, const float* __restrict__ cm,
    unsigned short* __restrict__ ctx) {
  __shared__ unsigned short Ks[256][40];   // [seq][d] pad->40
  __shared__ unsigned short Vt[32][264];   // [d][seq] pad->264
  __shared__ unsigned short Ps[4][64][72]; // wave-private P (also Vtmp/OsW)
  __shared__ float madd[256];
  const int b = blockIdx.x >> 3, h = blockIdx.x & 7;
  const int tid = threadIdx.x;
  const int wave = tid >> 6, lane = tid & 63;
  const int quad = lane >> 4, l15 = lane & 15;
  const size_t tokbase = (size_t)b * 256;
  const int hoff = h * 32;

  unsigned short* Vtmp = &Ps[0][0][0];  // [256][40] staging

#pragma unroll
  for (int it = 0; it < 4; ++it) {
    int idx = tid + it * 256;
    int row = idx >> 2, c = idx & 3;
    size_t g = (tokbase + row) * 256 + hoff + c * 8;
    *(uint4*)&Ks[row][c * 8] = *(const uint4*)(k + g);
    *(uint4*)(Vtmp + row * 40 + c * 8) = *(const uint4*)(v + g);
  }
  madd[tid] = (1.f - cm[b * 256 + tid]) * VERY_NEG;
  __syncthreads();
#pragma unroll
  for (int it = 0; it < 4; ++it) {
    int idx = tid + it * 256;
    int row = idx & 255, c = idx >> 8;
    uint4 w = *(const uint4*)(Vtmp + row * 40 + c * 8);
    const unsigned short* wsp = (const unsigned short*)&w;
#pragma unroll
    for (int j = 0; j < 8; ++j) Vt[c * 8 + j][row] = wsp[j];
  }
  __syncthreads();

  short8 qf[4];
#pragma unroll
  for (int mt = 0; mt < 4; ++mt) {
    size_t qrow = tokbase + wave * 64 + mt * 16 + l15;
    qf[mt] = *(const short8*)(q + qrow * 256 + hoff + quad * 8);
  }
  float madd_r[16];
#pragma unroll
  for (int nt = 0; nt < 16; ++nt) madd_r[nt] = madd[nt * 16 + l15];

  float m_r[4][4], l_r[4][4];
  floatx4 oa[4][2];
#pragma unroll
  for (int mt = 0; mt < 4; ++mt)
#pragma unroll
    for (int i = 0; i < 4; ++i) { m_r[mt][i] = -INFINITY; l_r[mt][i] = 0.f; }
#pragma unroll
  for (int mt = 0; mt < 4; ++mt)
#pragma unroll
    for (int nd = 0; nd < 2; ++nd) oa[mt][nd] = (floatx4){0.f, 0.f, 0.f, 0.f};

  const float scale = 0.17677669529663687f;  // 1/sqrt(32)

  for (int t = 0; t < 4; ++t) {
    short8 kf[4];
#pragma unroll
    for (int nt = 0; nt < 4; ++nt)
      kf[nt] = *(const short8*)&Ks[t * 64 + nt * 16 + l15][quad * 8];
    floatx4 sa[4][4];
#pragma unroll
    for (int mt = 0; mt < 4; ++mt)
#pragma unroll
      for (int nt = 0; nt < 4; ++nt) sa[mt][nt] = (floatx4){0.f, 0.f, 0.f, 0.f};
#pragma unroll
    for (int mt = 0; mt < 4; ++mt)
#pragma unroll
      for (int nt = 0; nt < 4; ++nt)
        sa[mt][nt] = __builtin_amdgcn_mfma_f32_16x16x32_bf16(
            qf[mt], kf[nt], sa[mt][nt], 0, 0, 0);

#pragma unroll
    for (int mt = 0; mt < 4; ++mt) {
#pragma unroll
      for (int i = 0; i < 4; ++i) {
        float rmax = -INFINITY;
#pragma unroll
        for (int nt = 0; nt < 4; ++nt) {
          float sv = sa[mt][nt][i] * scale + madd_r[t * 4 + nt];
          sa[mt][nt][i] = sv;
          rmax = fmaxf(rmax, sv);
        }
        rmax = fmaxf(rmax, __shfl_xor(rmax, 1, 64));
        rmax = fmaxf(rmax, __shfl_xor(rmax, 2, 64));
        rmax = fmaxf(rmax, __shfl_xor(rmax, 4, 64));
        rmax = fmaxf(rmax, __shfl_xor(rmax, 8, 64));
        float mn = fmaxf(m_r[mt][i], rmax);
        float alpha = __expf(m_r[mt][i] - mn);
        m_r[mt][i] = mn;
        float rs = 0.f;
#pragma unroll
        for (int nt = 0; nt < 4; ++nt) {
          float p = __expf(sa[mt][nt][i] - mn);
          sa[mt][nt][i] = p;
          rs += p;
        }
        rs += __shfl_xor(rs, 1, 64);
        rs += __shfl_xor(rs, 2, 64);
        rs += __shfl_xor(rs, 4, 64);
        rs += __shfl_xor(rs, 8, 64);
        l_r[mt][i] = l_r[mt][i] * alpha + rs;
#pragma unroll
        for (int nd = 0; nd < 2; ++nd) oa[mt][nd][i] *= alpha;
      }
    }
#pragma unroll
    for (int mt = 0; mt < 4; ++mt)
#pragma unroll
      for (int nt = 0; nt < 4; ++nt)
#pragma unroll
        for (int i = 0; i < 4; ++i)
          Ps[wave][mt * 16 + quad * 4 + i][nt * 16 + l15] =
              f2bf(sa[mt][nt][i]);
    __asm__ __volatile__("s_waitcnt lgkmcnt(0)" ::: "memory");
#pragma unroll
    for (int ks = 0; ks < 2; ++ks) {
      short8 vf[2];
#pragma unroll
      for (int nd = 0; nd < 2; ++nd)
        vf[nd] =
            *(const short8*)&Vt[nd * 16 + l15][t * 64 + ks * 32 + quad * 8];
#pragma unroll
      for (int mt = 0; mt < 4; ++mt) {
        short8 pf = *(const short8*)&Ps[wave][mt * 16 + l15][ks * 32 + quad * 8];
#pragma unroll
        for (int nd = 0; nd < 2; ++nd)
          oa[mt][nd] = __builtin_amdgcn_mfma_f32_16x16x32_bf16(
              pf, vf[nd], oa[mt][nd], 0, 0, 0);
      }
    }
    __asm__ __volatile__("s_waitcnt lgkmcnt(0)" ::: "memory");
  }

  unsigned short* OsW = &Ps[wave][0][0];
#pragma unroll
  for (int mt = 0; mt < 4; ++mt)
#pragma unroll
    for (int nd = 0; nd < 2; ++nd)
#pragma unroll
      for (int i = 0; i < 4; ++i)
        OsW[(mt * 16 + quad * 4 + i) * 40 + nd * 16 + l15] =
            f2bf(oa[mt][nd][i] / l_r[mt][i]);
  __asm__ __volatile__("s_waitcnt lgkmcnt(0)" ::: "memory");
#pragma unroll
  for (int it = 0; it < 4; ++it) {
    int idx = it * 64 + lane;
    int row = idx >> 2, c = idx & 3;
    uint4 w = *(const uint4*)(OsW + row * 40 + c * 8);
    *(uint4*)(ctx + (tokbase + wave * 64 + row) * 256 + hoff + c * 8) = w;
  }
}

// ---------------------------------------------------------------------------
// Attention pooling. 128 blocks (one per batch), 256 thr.
// ---------------------------------------------------------------------------
__global__ __launch_bounds__(256) void pool_kernel(
    const float* __restrict__ x, const float* __restrict__ code_mask,
    const float* __restrict__ pw, const float* __restrict__ pb,
    float* __restrict__ out) {
  const int b = blockIdx.x;
  const int t = threadIdx.x;
  __shared__ float ss[256];
  __shared__ float red[256];
  __shared__ float als[256];
  const float* xb = x + (size_t)b * 256 * 256;

  float s = pb[0];
  for (int j = 0; j < 256; j += 4) {
    float4 xv = *(const float4*)(xb + (size_t)t * 256 + j);
    float4 wv = *(const float4*)(pw + j);
    s += xv.x * wv.x + xv.y * wv.y + xv.z * wv.z + xv.w * wv.w;
  }
  s += (1.f - code_mask[b * 256 + t]) * VERY_NEG;
  ss[t] = s; red[t] = s;
  __syncthreads();
  for (int off = 128; off > 0; off >>= 1) {
    if (t < off) red[t] = fmaxf(red[t], red[t + off]);
    __syncthreads();
  }
  float m = red[0];
  __syncthreads();
  float e = __expf(ss[t] - m);
  als[t] = e; red[t] = e;
  __syncthreads();
  for (int off = 128; off > 0; off >>= 1) {
    if (t < off) red[t] += red[t + off];
    __syncthreads();
  }
  float inv = 1.f / red[0];
  float o = 0.f;
  for (int si = 0; si < 256; ++si) o += als[si] * xb[(size_t)si * 256 + t];
  out[b * 256 + t] = o * inv;
}

// ---------------------------------------------------------------------------
extern "C" void kernel_launch(void* const* d_in, const int* in_sizes, int n_in,
                              void* d_out, int out_size, void* d_ws,
                              size_t ws_size, hipStream_t stream) {
  const int* input_ids = (const int*)d_in[0];
  const float* code_mask = (const float*)d_in[1];
  const int* dx_leaves = (const int*)d_in[2];
  const int* dx_anc = (const int*)d_in[3];
  const float* dx_masks = (const float*)d_in[4];
  const float* embed_init_w = (const float*)d_in[5];
  const float* embed_inputs_w = (const float*)d_in[6];
  const float* attn_w1 = (const float*)d_in[7];
  const float* attn_b1 = (const float*)d_in[8];
  const float* attn_w2 = (const float*)d_in[9];
  const float* attn_b2 = (const float*)d_in[10];
  const float* pool_w = (const float*)d_in[11];
  const float* pool_b = (const float*)d_in[12];

  float* out = (float*)d_out;
  float* ws = (float*)d_ws;

  // workspace layout (floats)
  float* dict = ws;                      // 5,120,256
  float* xbuf = dict + 5120256;          // 8,388,608
  float* qb   = xbuf + 8388608;          // 8,388,608
  float* kb   = qb + 8388608;            // 8,388,608
  float* vb   = kb + 8388608;            // 8,388,608
  float* ctxb = vb + 8388608;            // 8,388,608
  float* wend = ctxb + 8388608;          // weight area (393,216 floats)

  // DAG-phase aliases over the (currently dead) xbuf region:
  float* sbuf = xbuf;                                   // 4*Rc = 640,000
  unsigned short* w1T_dag = (unsigned short*)(xbuf + 700000);  // 131,072 ush

  // encoder-phase aliases:
  unsigned short* xb16  = (unsigned short*)ctxb;  // bf16(x) pre-QKV, later ctx
  unsigned short* qkv16 = (unsigned short*)qb;    // q/k/v bf16, 16777216 stride
  unsigned short* xq16  = (unsigned short*)qb;    // bf16(x) post-WO (q dead)
  unsigned short* hid16 = (unsigned short*)kb;    // FFN hidden [32768][1024] (k+v)
  // bf16 weights:
  unsigned short* qkvT = (unsigned short*)wend;   // 196,608
  unsigned short* woT  = qkvT + 196608;           // 65,536
  unsigned short* fw1T = woT + 65536;             // 262,144
  unsigned short* fw2T = fw1T + 262144;           // 262,144

  // 1) DAG embedding -> dict_matrix (fused gather+MFMA pipeline)
  prep_w1T<<<512, 256, 0, stream>>>(attn_w1, w1T_dag);
  mlp_gemm<<<dim3(2, Rc / 128), 256, 0, stream>>>(dx_leaves, dx_anc, dx_masks,
                                                  embed_init_w, w1T_dag,
                                                  attn_b1, attn_w2, sbuf);
  dag_finalize<<<Cc, 256, 0, stream>>>(sbuf, dx_masks, dx_anc, attn_b2,
                                       embed_init_w, dict);

  auto run_encoder = [&](const float* wq, const float* wk, const float* wv,
                         const float* wo, const float* fw1, const float* fb1,
                         const float* fw2, const float* fb2, float* final_out) {
    prep_weights<<<3072, 256, 0, stream>>>(wq, wk, wv, wo, fw1, fw2, qkvT,
                                           woT, fw1T, fw2T);
    // fused QKV: N=768, bf16 split-output into q/k/v buffers
    gemm_mfma<256, false, false, false, 3><<<dim3(6, 256), 256, 0, stream>>>(
        xb16, qkvT, nullptr, nullptr, nullptr, qkv16, 256);
    // MFMA flash attention -> bf16 ctx (into xb16 region; dead post-QKV)
    attn_mfma<<<Bc * NHc, 256, 0, stream>>>(qkv16, qkv16 + 16777216,
                                            qkv16 + 33554432, code_mask, xb16);
    // x += ctx @ wo  (fp32 resid out to xbuf, bf16 copy to xq16)
    gemm_mfma<256, false, false, true, 2><<<dim3(2, 256), 256, 0, stream>>>(
        xb16, woT, nullptr, xbuf, xbuf, xq16, 256);
    // FFN: hidden bf16 in dead k+v buffers
    gemm_mfma<256, true, true, false, 1><<<dim3(8, 256), 256, 0, stream>>>(
        xq16, fw1T, fb1, nullptr, nullptr, hid16, 1024);
    gemm_mfma<1024, true, false, true, 0><<<dim3(2, 256), 256, 0, stream>>>(
        hid16, fw2T, fb2, xbuf, final_out, nullptr, 256);
  };

  // 2) visit stream
  gather_both<<<8192, 256, 0, stream>>>(input_ids,
                                        (const float4*)embed_inputs_w,
                                        (float4*)xbuf, xb16);
  run_encoder((const float*)d_in[13], (const float*)d_in[14],
              (const float*)d_in[15], (const float*)d_in[16],
              (const float*)d_in[17], (const float*)d_in[18],
              (const float*)d_in[19], (const float*)d_in[20], out);

  // 3) dag stream
  gather_both<<<8192, 256, 0, stream>>>(input_ids, (const float4*)dict,
                                        (float4*)xbuf, xb16);
  run_encoder((const float*)d_in[21], (const float*)d_in[22],
              (const float*)d_in[23], (const float*)d_in[24],
              (const float*)d_in[25], (const float*)d_in[26],
              (const float*)d_in[27], (const float*)d_in[28], xbuf);

  pool_kernel<<<Bc, 256, 0, stream>>>(xbuf, code_mask, pool_w, pool_b,
                                      out + 8388608);
}